// Round 13
// baseline (110.714 us; speedup 1.0000x reference)
//
#include <hip/hip_runtime.h>
#include <hip/hip_bf16.h>

// ---------------------------------------------------------------------------
// Fused: GroupNorm -> QKV (1x1 conv) -> 8-head attention (n=1024,d=64)
//        -> proj (1x1 conv) + bias + residual(xn)
// b=8, c=512, n=1024, GROUPS=8, HEADS=8, dim_head=64. bf16 MFMA, fp32 accum.
// R13: attention in 8-wave/512-thread blocks (grid 256) -> 4 waves/SIMD
//      (was 2): doubles TLP for latency hiding at constant per-wave work.
//      GEMMs keep R12 global_load_lds staging.
// ---------------------------------------------------------------------------

typedef short bf16x8 __attribute__((ext_vector_type(8)));
typedef float f32x4 __attribute__((ext_vector_type(4)));
typedef unsigned short u16x4 __attribute__((ext_vector_type(4)));

#define MFMA16(a, b, c) __builtin_amdgcn_mfma_f32_16x16x32_bf16(a, b, c, 0, 0, 0)
#define EXP2(x) __builtin_amdgcn_exp2f(x)
// rotate-right by N within each 16-lane row (pure VALU DPP)
#define ROR16(v, N) __int_as_float(__builtin_amdgcn_mov_dpp(__float_as_int(v), 0x120 + (N), 0xF, 0xF, false))

__device__ __forceinline__ unsigned short f2bf(float f) {
    unsigned u = __float_as_uint(f);
    u += 0x7fffu + ((u >> 16) & 1u);   // round-to-nearest-even
    return (unsigned short)(u >> 16);
}

// pack two fp32 -> u32 of two bf16 (lo=a, hi=b), RNE via HIP intrinsic
__device__ __forceinline__ unsigned pk2(float a, float b) {
    __hip_bfloat162 h = __float22bfloat162_rn(float2{a, b});
    unsigned r;
    __builtin_memcpy(&r, &h, 4);
    return r;
}

// async global -> LDS, 16B per lane; lptr must be wave-uniform (HW adds lane*16)
__device__ __forceinline__ void glds16(const unsigned short* g, unsigned short* l) {
    __builtin_amdgcn_global_load_lds(
        (const __attribute__((address_space(1))) unsigned int*)g,
        (__attribute__((address_space(3))) unsigned int*)l, 16, 0, 0);
}

// ---------------- K0: fused groupnorm stats + weight bf16 conversion --------
// blocks 0..63: stats for (b,group) = blk; blocks 64..831: weight cvt.
__global__ __launch_bounds__(256) void prep_kern(
    const float* __restrict__ x, const float* __restrict__ wq,
    const float* __restrict__ wo, float2* __restrict__ stats,
    unsigned short* __restrict__ wqb, unsigned short* __restrict__ wob) {
    int blk = blockIdx.x, t = threadIdx.x;
    if (blk < 64) {
        __shared__ float ss[256], sq[256];
        const float4* p = reinterpret_cast<const float4*>(x + (size_t)blk * 65536);
        float s = 0.f, q = 0.f;
        for (int i = t; i < 16384; i += 256) {
            float4 v = p[i];
            s += v.x + v.y + v.z + v.w;
            q += v.x * v.x + v.y * v.y + v.z * v.z + v.w * v.w;
        }
        ss[t] = s; sq[t] = q; __syncthreads();
        for (int o = 128; o > 0; o >>= 1) {
            if (t < o) { ss[t] += ss[t + o]; sq[t] += sq[t + o]; }
            __syncthreads();
        }
        if (t == 0) {
            float mean = ss[0] * (1.f / 65536.f);
            float var  = sq[0] * (1.f / 65536.f) - mean * mean;
            stats[blk] = make_float2(mean, rsqrtf(var + 1e-5f));
        }
    } else {
        int i = (blk - 64) * 256 + t;         // 0..196607
        {
            float4 v = reinterpret_cast<const float4*>(wq)[i];
            unsigned short* d = wqb + (size_t)i * 4;
            d[0] = f2bf(v.x); d[1] = f2bf(v.y); d[2] = f2bf(v.z); d[3] = f2bf(v.w);
        }
        if (i < 65536) {
            float4 v = reinterpret_cast<const float4*>(wo)[i];
            unsigned short* d = wob + (size_t)i * 4;
            d[0] = f2bf(v.x); d[1] = f2bf(v.y); d[2] = f2bf(v.z); d[3] = f2bf(v.w);
        }
    }
}

// ---------------- K2: normalize + transpose -> xnT[b][n][c] bf16 ------------
__global__ __launch_bounds__(256) void gn_norm_t(
    const float* __restrict__ x, const float* __restrict__ gamma,
    const float* __restrict__ beta, const float2* __restrict__ stats,
    unsigned short* __restrict__ xnT) {
    __shared__ unsigned short tile[64 * 72];
    int t = threadIdx.x;
    int jt = blockIdx.x, ct = blockIdx.y, b = blockIdx.z;
    int c = t >> 2, jseg = (t & 3) * 16;
    float2 ms = stats[b * 8 + ct];
    int ch = ct * 64 + c;
    float g  = gamma[ch] * ms.y;
    float bb = beta[ch] - ms.x * g;
    const float* src = x + ((size_t)(b * 512 + ch)) * 1024 + jt * 64 + jseg;
    float4 v0 = *(const float4*)(src);
    float4 v1 = *(const float4*)(src + 4);
    float4 v2 = *(const float4*)(src + 8);
    float4 v3 = *(const float4*)(src + 12);
    float vv[16] = {v0.x,v0.y,v0.z,v0.w, v1.x,v1.y,v1.z,v1.w,
                    v2.x,v2.y,v2.z,v2.w, v3.x,v3.y,v3.z,v3.w};
    #pragma unroll
    for (int e = 0; e < 16; ++e)
        tile[(jseg + e) * 72 + c] = f2bf(fmaf(vv[e], g, bb));
    __syncthreads();
    int j = t >> 2, cseg = (t & 3) * 16;
    unsigned short* dst = xnT + ((size_t)b * 1024 + jt * 64 + j) * 512 + ct * 64 + cseg;
    bf16x8 a0 = *(const bf16x8*)&tile[j * 72 + cseg];
    bf16x8 a1 = *(const bf16x8*)&tile[j * 72 + cseg + 8];
    *(bf16x8*)dst = a0;
    *(bf16x8*)(dst + 8) = a1;
}

// ---------------- K3: QKV GEMM -> qT (scaled), kT, v ------------------------
// A = Wqkv bf16 [1536][512] row-major; B = xnT[b] [1024 j][512 c] row-major.
// qT,kT: [b*8+h][i/j][dd]  (dd contiguous);  v: [b*8+h][dd][j].
// Q pre-scaled by 0.125 * log2(e) so attention softmax runs in exp2 domain.
// Staging via global_load_lds into LINEAR LDS tiles (m97 pattern).
__global__ __launch_bounds__(256) void qkv_gemm(
    const unsigned short* __restrict__ W, const unsigned short* __restrict__ xnT,
    unsigned short* __restrict__ qT, unsigned short* __restrict__ kT,
    unsigned short* __restrict__ vK) {
    __shared__ unsigned short a_t[128 * 64];   // [o][k] linear
    __shared__ unsigned short b_t[128 * 64];   // [j][k] linear
    int t = threadIdx.x, w = t >> 6, l = t & 63, lr = l & 15, lg = l >> 4;
    int jt = blockIdx.x, mt = blockIdx.y, b = blockIdx.z;
    int o0 = mt * 128, j0 = jt * 128;
    int wr = w >> 1, wc = w & 1;
    const unsigned short* Bsrc = xnT + (size_t)b * 1024 * 512;
    f32x4 acc[4][4] = {};
    // glds source: lane l covers row w*32 + k*8 + (l>>3), cols (l&7)*8..+7
    const unsigned short* gA = W    + (size_t)(o0 + w * 32 + (l >> 3)) * 512 + (l & 7) * 8;
    const unsigned short* gB = Bsrc + (size_t)(j0 + w * 32 + (l >> 3)) * 512 + (l & 7) * 8;
    for (int kk = 0; kk < 512; kk += 64) {
        #pragma unroll
        for (int k = 0; k < 4; ++k) {
            glds16(gA + (size_t)k * 4096 + kk, a_t + w * 2048 + k * 512);
            glds16(gB + (size_t)k * 4096 + kk, b_t + w * 2048 + k * 512);
        }
        __syncthreads();                       // drains vmcnt -> LDS filled
        __builtin_amdgcn_s_setprio(1);
        #pragma unroll
        for (int ks = 0; ks < 2; ++ks) {
            bf16x8 af[4], bfr[4];
            #pragma unroll
            for (int m = 0; m < 4; ++m)
                af[m] = *(const bf16x8*)&a_t[(wr * 64 + m * 16 + lr) * 64 + ks * 32 + lg * 8];
            #pragma unroll
            for (int n = 0; n < 4; ++n)
                bfr[n] = *(const bf16x8*)&b_t[(wc * 64 + n * 16 + lr) * 64 + ks * 32 + lg * 8];
            #pragma unroll
            for (int m = 0; m < 4; ++m)
                #pragma unroll
                for (int n = 0; n < 4; ++n)
                    acc[m][n] = MFMA16(af[m], bfr[n], acc[m][n]);
        }
        __builtin_amdgcn_s_setprio(0);
        __syncthreads();                       // all reads done before next glds
    }
    int part = mt >> 2;                       // 0=q, 1=k, 2=v
    int hh = ((mt * 2) + wr) & 7;             // head for this wave-row half
    if (part < 2) {
        unsigned short* dst = (part == 0) ? qT : kT;
        float sc = (part == 0) ? 0.1803368801f : 1.0f;  // 0.125*log2(e)
        #pragma unroll
        for (int m = 0; m < 4; ++m)
            #pragma unroll
            for (int n = 0; n < 4; ++n) {
                int j = j0 + wc * 64 + n * 16 + lr;
                u16x4 pkt;
                pkt[0] = f2bf(acc[m][n][0] * sc);
                pkt[1] = f2bf(acc[m][n][1] * sc);
                pkt[2] = f2bf(acc[m][n][2] * sc);
                pkt[3] = f2bf(acc[m][n][3] * sc);
                *(u16x4*)&dst[(((size_t)(b * 8 + hh)) * 1024 + j) * 64 + m * 16 + lg * 4] = pkt;
            }
    } else {
        #pragma unroll
        for (int m = 0; m < 4; ++m)
            #pragma unroll
            for (int n = 0; n < 4; ++n)
                #pragma unroll
                for (int r = 0; r < 4; ++r) {
                    int dd = m * 16 + lg * 4 + r;
                    int j = j0 + wc * 64 + n * 16 + lr;
                    vK[(((size_t)(b * 8 + hh)) * 64 + dd) * 1024 + j] = f2bf(acc[m][n][r]);
                }
    }
}

// ---------------- K4: flash attention, 8 waves x 32 q-rows, dbuf LDS --------
// Grid 256 x 512 threads: 2 blocks/CU x 8 waves = 4 waves/SIMD (2x R12's TLP).
// One barrier per K/V tile: {barrier; write buf[(t+1)&1]; prefetch t+2;
// compute tile t from buf[t&1]}. setprio(1) around MFMA clusters.
__global__ __launch_bounds__(512, 4) void attn_kern(
    const unsigned short* __restrict__ qT, const unsigned short* __restrict__ kT,
    const unsigned short* __restrict__ vK, unsigned short* __restrict__ o_t) {
    __shared__ unsigned short k_t[2 * 64 * 72];   // [buf][j][dd]
    __shared__ unsigned short v_s[2 * 64 * 72];   // [buf][dd][j]
    __shared__ unsigned short p_s[8 * 32 * 72];   // per-wave [i][j]
    int t = threadIdx.x, w = t >> 6, l = t & 63, lr = l & 15, lg = (l >> 4) & 3;
    // XCD-chunked swizzle: 32 consecutive decoded blocks (8 bh) per XCD
    int id = blockIdx.x;
    int lin = (id & 7) * 32 + (id >> 3);
    int qt = lin & 3, bh = lin >> 2;
    int b = bh >> 3, h = bh & 7;
    const unsigned short* qb = qT + (size_t)bh * 1024 * 64;
    const unsigned short* kb = kT + (size_t)bh * 1024 * 64;
    const unsigned short* vb = vK + (size_t)bh * 64 * 1024;
    int i0 = qt * 256 + w * 32;

    // Q fragments: A[row=i][k=dd], rows i0 + it*16 + lr  (b128 loads)
    bf16x8 aq[2][2];
    #pragma unroll
    for (int it = 0; it < 2; ++it)
        #pragma unroll
        for (int kt = 0; kt < 2; ++kt)
            aq[it][kt] = *(const bf16x8*)&qb[(size_t)(i0 + it * 16 + lr) * 64 + kt * 32 + lg * 8];

    bf16x8 ones;
    #pragma unroll
    for (int e = 0; e < 8; ++e) ones[e] = (short)0x3F80;   // bf16 1.0

    float m8[2][4];
    #pragma unroll
    for (int it = 0; it < 2; ++it)
        #pragma unroll
        for (int r = 0; r < 4; ++r) m8[it][r] = -3.0e38f;
    f32x4 accO[2][4] = {};
    f32x4 accL[2] = {};
    unsigned short* pw = p_s + w * (32 * 72);

    // staging: thread t stages 16B of K and 16B of V per tile
    int srow = t >> 3, scol = (t & 7) * 8;
    const unsigned short* kg = kb + srow * 64 + scol;            // K row j=srow
    const unsigned short* vg = vb + (size_t)srow * 1024 + scol;  // V row dd=srow
    int soff = srow * 72 + scol;

    // prologue: tile 0 -> buf0 directly; tile 1 -> regs
    {
        bf16x8 a0 = *(const bf16x8*)kg;
        bf16x8 c0 = *(const bf16x8*)vg;
        *(bf16x8*)&k_t[soff] = a0;
        *(bf16x8*)&v_s[soff] = c0;
    }
    bf16x8 nk0 = *(const bf16x8*)(kg + 4096);
    bf16x8 nv0 = *(const bf16x8*)(vg + 64);

    for (int tile = 0; tile < 16; ++tile) {
        __syncthreads();                       // buf[tile&1] ready; buf[(tile+1)&1] free
        const unsigned short* kc = k_t + (tile & 1) * 4608;
        const unsigned short* vc = v_s + (tile & 1) * 4608;
        if (tile < 15) {
            *(bf16x8*)(k_t + ((tile + 1) & 1) * 4608 + soff) = nk0;
            *(bf16x8*)(v_s + ((tile + 1) & 1) * 4608 + soff) = nv0;
            if (tile < 14) {                   // prefetch tile+2 (hides under compute)
                nk0 = *(const bf16x8*)(kg + (tile + 2) * 4096);
                nv0 = *(const bf16x8*)(vg + (tile + 2) * 64);
            }
        }

        // S = Q K^T  (log2 domain) — bk shared by both i-tiles
        f32x4 s[2][4] = {};
        __builtin_amdgcn_s_setprio(1);
        #pragma unroll
        for (int kt = 0; kt < 2; ++kt) {
            bf16x8 bk[4];
            #pragma unroll
            for (int jt = 0; jt < 4; ++jt)
                bk[jt] = *(const bf16x8*)&kc[(jt * 16 + lr) * 72 + kt * 32 + lg * 8];
            #pragma unroll
            for (int it = 0; it < 2; ++it)
                #pragma unroll
                for (int jt = 0; jt < 4; ++jt)
                    s[it][jt] = MFMA16(aq[it][kt], bk[jt], s[it][jt]);
        }
        __builtin_amdgcn_s_setprio(0);

        // per-row tile max via DPP; defer-max: rescale only on growth
        float sm[2][4];
        float g = -3.0e38f;
        #pragma unroll
        for (int it = 0; it < 2; ++it)
            #pragma unroll
            for (int r = 0; r < 4; ++r) {
                float v0 = fmaxf(fmaxf(s[it][0][r], s[it][1][r]),
                                 fmaxf(s[it][2][r], s[it][3][r]));
                v0 = fmaxf(v0, ROR16(v0, 1));
                v0 = fmaxf(v0, ROR16(v0, 2));
                v0 = fmaxf(v0, ROR16(v0, 4));
                v0 = fmaxf(v0, ROR16(v0, 8));
                sm[it][r] = v0;
                g = fmaxf(g, v0 - m8[it][r]);
            }
        if (__any(g > 11.0f)) {
            #pragma unroll
            for (int it = 0; it < 2; ++it)
                #pragma unroll
                for (int r = 0; r < 4; ++r) {
                    float mn = fmaxf(m8[it][r], sm[it][r]);
                    float al = EXP2(m8[it][r] - mn);
                    accL[it][r] *= al;
                    #pragma unroll
                    for (int dt = 0; dt < 4; ++dt) accO[it][dt][r] *= al;
                    m8[it][r] = mn;
                }
        }

        // P = exp2(S - m), pack to bf16 in wave-private LDS
        #pragma unroll
        for (int it = 0; it < 2; ++it)
            #pragma unroll
            for (int jt = 0; jt < 4; ++jt) {
                unsigned u01 = pk2(EXP2(s[it][jt][0] - m8[it][0]),
                                   EXP2(s[it][jt][1] - m8[it][1]));
                unsigned u23 = pk2(EXP2(s[it][jt][2] - m8[it][2]),
                                   EXP2(s[it][jt][3] - m8[it][3]));
                int row = it * 16 + lg * 4;
                int col = jt * 16 + lr;
                pw[(row + 0) * 72 + col] = (unsigned short)u01;
                pw[(row + 1) * 72 + col] = (unsigned short)(u01 >> 16);
                pw[(row + 2) * 72 + col] = (unsigned short)u23;
                pw[(row + 3) * 72 + col] = (unsigned short)(u23 >> 16);
            }

        // O += P V^T ; L += P * 1  — bv shared by both i-tiles
        __builtin_amdgcn_s_setprio(1);
        #pragma unroll
        for (int kj = 0; kj < 2; ++kj) {
            bf16x8 bv[4];
            #pragma unroll
            for (int dt = 0; dt < 4; ++dt)
                bv[dt] = *(const bf16x8*)&vc[(dt * 16 + lr) * 72 + kj * 32 + lg * 8];
            #pragma unroll
            for (int it = 0; it < 2; ++it) {
                bf16x8 pa = *(const bf16x8*)&pw[(it * 16 + lr) * 72 + kj * 32 + lg * 8];
                accL[it] = MFMA16(pa, ones, accL[it]);
                #pragma unroll
                for (int dt = 0; dt < 4; ++dt)
                    accO[it][dt] = MFMA16(pa, bv[dt], accO[it][dt]);
            }
        }
        __builtin_amdgcn_s_setprio(0);
    }

    // epilogue: o_t[b][i][h*64+dd] = O[i][dd] / l
    #pragma unroll
    for (int it = 0; it < 2; ++it) {
        float inv[4];
        #pragma unroll
        for (int r = 0; r < 4; ++r) inv[r] = 1.0f / accL[it][r];
        #pragma unroll
        for (int dt = 0; dt < 4; ++dt)
            #pragma unroll
            for (int r = 0; r < 4; ++r) {
                int i = i0 + it * 16 + lg * 4 + r;
                o_t[((size_t)b * 1024 + i) * 512 + h * 64 + dt * 16 + lr] =
                    f2bf(accO[it][dt][r] * inv[r]);
            }
    }
}

// ---------------- K5: proj GEMM + bias + residual(xn) -----------------------
// Same global_load_lds staging as qkv_gemm.
__global__ __launch_bounds__(256) void proj_gemm(
    const unsigned short* __restrict__ W, const unsigned short* __restrict__ o_t,
    const float* __restrict__ b_out, const float* __restrict__ x,
    const float* __restrict__ gamma, const float* __restrict__ beta,
    const float2* __restrict__ stats, float* __restrict__ out) {
    __shared__ unsigned short a_t[128 * 64];
    __shared__ unsigned short b_t[128 * 64];
    int t = threadIdx.x, w = t >> 6, l = t & 63, lr = l & 15, lg = l >> 4;
    int jt = blockIdx.x, mt = blockIdx.y, b = blockIdx.z;
    int o0 = mt * 128, j0 = jt * 128;
    int wr = w >> 1, wc = w & 1;
    const unsigned short* Bsrc = o_t + (size_t)b * 1024 * 512;
    f32x4 acc[4][4] = {};
    const unsigned short* gA = W    + (size_t)(o0 + w * 32 + (l >> 3)) * 512 + (l & 7) * 8;
    const unsigned short* gB = Bsrc + (size_t)(j0 + w * 32 + (l >> 3)) * 512 + (l & 7) * 8;
    for (int kk = 0; kk < 512; kk += 64) {
        #pragma unroll
        for (int k = 0; k < 4; ++k) {
            glds16(gA + (size_t)k * 4096 + kk, a_t + w * 2048 + k * 512);
            glds16(gB + (size_t)k * 4096 + kk, b_t + w * 2048 + k * 512);
        }
        __syncthreads();
        __builtin_amdgcn_s_setprio(1);
        #pragma unroll
        for (int ks = 0; ks < 2; ++ks) {
            bf16x8 af[4], bfr[4];
            #pragma unroll
            for (int m = 0; m < 4; ++m)
                af[m] = *(const bf16x8*)&a_t[(wr * 64 + m * 16 + lr) * 64 + ks * 32 + lg * 8];
            #pragma unroll
            for (int n = 0; n < 4; ++n)
                bfr[n] = *(const bf16x8*)&b_t[(wc * 64 + n * 16 + lr) * 64 + ks * 32 + lg * 8];
            #pragma unroll
            for (int m = 0; m < 4; ++m)
                #pragma unroll
                for (int n = 0; n < 4; ++n)
                    acc[m][n] = MFMA16(af[m], bfr[n], acc[m][n]);
        }
        __builtin_amdgcn_s_setprio(0);
        __syncthreads();
    }
    #pragma unroll
    for (int m = 0; m < 4; ++m)
        #pragma unroll
        for (int r = 0; r < 4; ++r) {
            int o = o0 + wr * 64 + m * 16 + lg * 4 + r;
            float2 ms = stats[b * 8 + (o >> 6)];
            float g  = gamma[o] * ms.y;
            float bb = beta[o] - ms.x * g + b_out[o];
            const float* xr = x + ((size_t)b * 512 + o) * 1024;
            #pragma unroll
            for (int n = 0; n < 4; ++n) {
                int j = j0 + wc * 64 + n * 16 + lr;
                float xn = fmaf(xr[j], g, bb);
                out[((size_t)b * 512 + o) * 1024 + j] = acc[m][n][r] + xn;
            }
        }
}

// ---------------------------------------------------------------------------
extern "C" void kernel_launch(void* const* d_in, const int* in_sizes, int n_in,
                              void* d_out, int out_size, void* d_ws, size_t ws_size,
                              hipStream_t stream) {
    const float* x     = (const float*)d_in[0];
    const float* gamma = (const float*)d_in[1];
    const float* beta  = (const float*)d_in[2];
    const float* w_qkv = (const float*)d_in[3];
    const float* w_out = (const float*)d_in[4];
    const float* b_out = (const float*)d_in[5];
    float* out = (float*)d_out;

    char* ws = (char*)d_ws;
    unsigned short* wqb   = (unsigned short*)(ws);                    // 1.5 MB
    unsigned short* wob   = (unsigned short*)(ws + 0x180000);         // 0.5 MB
    float2*         stats = (float2*)(ws + 0x200000);                 // 512 B
    unsigned short* xnT   = (unsigned short*)(ws + 0x210000);         // 8 MB
    unsigned short* qT    = (unsigned short*)(ws + 0xA10000);         // 8 MB
    unsigned short* kT    = (unsigned short*)(ws + 0x1210000);        // 8 MB
    unsigned short* vK    = (unsigned short*)(ws + 0x1A10000);        // 8 MB
    unsigned short* o_t   = (unsigned short*)(ws + 0x2210000);        // 8 MB
    // total ~44.1 MB

    prep_kern<<<832, 256, 0, stream>>>(x, w_qkv, w_out, stats, wqb, wob);
    gn_norm_t<<<dim3(16, 8, 8), 256, 0, stream>>>(x, gamma, beta, stats, xnT);
    qkv_gemm<<<dim3(8, 12, 8), 256, 0, stream>>>(wqb, xnT, qT, kT, vK);
    attn_kern<<<256, 512, 0, stream>>>(qT, kT, vK, o_t);
    proj_gemm<<<dim3(8, 4, 8), 256, 0, stream>>>(wob, o_t, b_out, x, gamma, beta, stats, out);
}

// Round 14
// 105.900 us; speedup vs baseline: 1.0455x; 1.0455x over previous
//
#include <hip/hip_runtime.h>
#include <hip/hip_bf16.h>

// ---------------------------------------------------------------------------
// Fused: GroupNorm -> QKV (1x1 conv) -> 8-head attention (n=1024,d=64)
//        -> proj (1x1 conv) + bias + residual(xn)
// b=8, c=512, n=1024, GROUPS=8, HEADS=8, dim_head=64. bf16 MFMA, fp32 accum.
// R14: revert to R12 (best verified: 104.8 us). R13's 8-wave blocks could not
//      raise waves/SIMD (total waves fixed at 2048 by problem geometry) and
//      added 8-wave barrier cost. GEMMs: global_load_lds staging; attention:
//      4 waves x 32 q-rows, dbuf LDS, 1 barrier/tile, setprio.
// ---------------------------------------------------------------------------

typedef short bf16x8 __attribute__((ext_vector_type(8)));
typedef float f32x4 __attribute__((ext_vector_type(4)));
typedef unsigned short u16x4 __attribute__((ext_vector_type(4)));

#define MFMA16(a, b, c) __builtin_amdgcn_mfma_f32_16x16x32_bf16(a, b, c, 0, 0, 0)
#define EXP2(x) __builtin_amdgcn_exp2f(x)
// rotate-right by N within each 16-lane row (pure VALU DPP)
#define ROR16(v, N) __int_as_float(__builtin_amdgcn_mov_dpp(__float_as_int(v), 0x120 + (N), 0xF, 0xF, false))

__device__ __forceinline__ unsigned short f2bf(float f) {
    unsigned u = __float_as_uint(f);
    u += 0x7fffu + ((u >> 16) & 1u);   // round-to-nearest-even
    return (unsigned short)(u >> 16);
}

// pack two fp32 -> u32 of two bf16 (lo=a, hi=b), RNE via HIP intrinsic
__device__ __forceinline__ unsigned pk2(float a, float b) {
    __hip_bfloat162 h = __float22bfloat162_rn(float2{a, b});
    unsigned r;
    __builtin_memcpy(&r, &h, 4);
    return r;
}

// async global -> LDS, 16B per lane; lptr must be wave-uniform (HW adds lane*16)
__device__ __forceinline__ void glds16(const unsigned short* g, unsigned short* l) {
    __builtin_amdgcn_global_load_lds(
        (const __attribute__((address_space(1))) unsigned int*)g,
        (__attribute__((address_space(3))) unsigned int*)l, 16, 0, 0);
}

// ---------------- K0: fused groupnorm stats + weight bf16 conversion --------
// blocks 0..63: stats for (b,group) = blk; blocks 64..831: weight cvt.
__global__ __launch_bounds__(256) void prep_kern(
    const float* __restrict__ x, const float* __restrict__ wq,
    const float* __restrict__ wo, float2* __restrict__ stats,
    unsigned short* __restrict__ wqb, unsigned short* __restrict__ wob) {
    int blk = blockIdx.x, t = threadIdx.x;
    if (blk < 64) {
        __shared__ float ss[256], sq[256];
        const float4* p = reinterpret_cast<const float4*>(x + (size_t)blk * 65536);
        float s = 0.f, q = 0.f;
        for (int i = t; i < 16384; i += 256) {
            float4 v = p[i];
            s += v.x + v.y + v.z + v.w;
            q += v.x * v.x + v.y * v.y + v.z * v.z + v.w * v.w;
        }
        ss[t] = s; sq[t] = q; __syncthreads();
        for (int o = 128; o > 0; o >>= 1) {
            if (t < o) { ss[t] += ss[t + o]; sq[t] += sq[t + o]; }
            __syncthreads();
        }
        if (t == 0) {
            float mean = ss[0] * (1.f / 65536.f);
            float var  = sq[0] * (1.f / 65536.f) - mean * mean;
            stats[blk] = make_float2(mean, rsqrtf(var + 1e-5f));
        }
    } else {
        int i = (blk - 64) * 256 + t;         // 0..196607
        {
            float4 v = reinterpret_cast<const float4*>(wq)[i];
            unsigned short* d = wqb + (size_t)i * 4;
            d[0] = f2bf(v.x); d[1] = f2bf(v.y); d[2] = f2bf(v.z); d[3] = f2bf(v.w);
        }
        if (i < 65536) {
            float4 v = reinterpret_cast<const float4*>(wo)[i];
            unsigned short* d = wob + (size_t)i * 4;
            d[0] = f2bf(v.x); d[1] = f2bf(v.y); d[2] = f2bf(v.z); d[3] = f2bf(v.w);
        }
    }
}

// ---------------- K2: normalize + transpose -> xnT[b][n][c] bf16 ------------
__global__ __launch_bounds__(256) void gn_norm_t(
    const float* __restrict__ x, const float* __restrict__ gamma,
    const float* __restrict__ beta, const float2* __restrict__ stats,
    unsigned short* __restrict__ xnT) {
    __shared__ unsigned short tile[64 * 72];
    int t = threadIdx.x;
    int jt = blockIdx.x, ct = blockIdx.y, b = blockIdx.z;
    int c = t >> 2, jseg = (t & 3) * 16;
    float2 ms = stats[b * 8 + ct];
    int ch = ct * 64 + c;
    float g  = gamma[ch] * ms.y;
    float bb = beta[ch] - ms.x * g;
    const float* src = x + ((size_t)(b * 512 + ch)) * 1024 + jt * 64 + jseg;
    float4 v0 = *(const float4*)(src);
    float4 v1 = *(const float4*)(src + 4);
    float4 v2 = *(const float4*)(src + 8);
    float4 v3 = *(const float4*)(src + 12);
    float vv[16] = {v0.x,v0.y,v0.z,v0.w, v1.x,v1.y,v1.z,v1.w,
                    v2.x,v2.y,v2.z,v2.w, v3.x,v3.y,v3.z,v3.w};
    #pragma unroll
    for (int e = 0; e < 16; ++e)
        tile[(jseg + e) * 72 + c] = f2bf(fmaf(vv[e], g, bb));
    __syncthreads();
    int j = t >> 2, cseg = (t & 3) * 16;
    unsigned short* dst = xnT + ((size_t)b * 1024 + jt * 64 + j) * 512 + ct * 64 + cseg;
    bf16x8 a0 = *(const bf16x8*)&tile[j * 72 + cseg];
    bf16x8 a1 = *(const bf16x8*)&tile[j * 72 + cseg + 8];
    *(bf16x8*)dst = a0;
    *(bf16x8*)(dst + 8) = a1;
}

// ---------------- K3: QKV GEMM -> qT (scaled), kT, v ------------------------
// A = Wqkv bf16 [1536][512] row-major; B = xnT[b] [1024 j][512 c] row-major.
// qT,kT: [b*8+h][i/j][dd]  (dd contiguous);  v: [b*8+h][dd][j].
// Q pre-scaled by 0.125 * log2(e) so attention softmax runs in exp2 domain.
// Staging via global_load_lds into LINEAR LDS tiles (m97 pattern).
__global__ __launch_bounds__(256) void qkv_gemm(
    const unsigned short* __restrict__ W, const unsigned short* __restrict__ xnT,
    unsigned short* __restrict__ qT, unsigned short* __restrict__ kT,
    unsigned short* __restrict__ vK) {
    __shared__ unsigned short a_t[128 * 64];   // [o][k] linear
    __shared__ unsigned short b_t[128 * 64];   // [j][k] linear
    int t = threadIdx.x, w = t >> 6, l = t & 63, lr = l & 15, lg = l >> 4;
    int jt = blockIdx.x, mt = blockIdx.y, b = blockIdx.z;
    int o0 = mt * 128, j0 = jt * 128;
    int wr = w >> 1, wc = w & 1;
    const unsigned short* Bsrc = xnT + (size_t)b * 1024 * 512;
    f32x4 acc[4][4] = {};
    // glds source: lane l covers row w*32 + k*8 + (l>>3), cols (l&7)*8..+7
    const unsigned short* gA = W    + (size_t)(o0 + w * 32 + (l >> 3)) * 512 + (l & 7) * 8;
    const unsigned short* gB = Bsrc + (size_t)(j0 + w * 32 + (l >> 3)) * 512 + (l & 7) * 8;
    for (int kk = 0; kk < 512; kk += 64) {
        #pragma unroll
        for (int k = 0; k < 4; ++k) {
            glds16(gA + (size_t)k * 4096 + kk, a_t + w * 2048 + k * 512);
            glds16(gB + (size_t)k * 4096 + kk, b_t + w * 2048 + k * 512);
        }
        __syncthreads();                       // drains vmcnt -> LDS filled
        __builtin_amdgcn_s_setprio(1);
        #pragma unroll
        for (int ks = 0; ks < 2; ++ks) {
            bf16x8 af[4], bfr[4];
            #pragma unroll
            for (int m = 0; m < 4; ++m)
                af[m] = *(const bf16x8*)&a_t[(wr * 64 + m * 16 + lr) * 64 + ks * 32 + lg * 8];
            #pragma unroll
            for (int n = 0; n < 4; ++n)
                bfr[n] = *(const bf16x8*)&b_t[(wc * 64 + n * 16 + lr) * 64 + ks * 32 + lg * 8];
            #pragma unroll
            for (int m = 0; m < 4; ++m)
                #pragma unroll
                for (int n = 0; n < 4; ++n)
                    acc[m][n] = MFMA16(af[m], bfr[n], acc[m][n]);
        }
        __builtin_amdgcn_s_setprio(0);
        __syncthreads();                       // all reads done before next glds
    }
    int part = mt >> 2;                       // 0=q, 1=k, 2=v
    int hh = ((mt * 2) + wr) & 7;             // head for this wave-row half
    if (part < 2) {
        unsigned short* dst = (part == 0) ? qT : kT;
        float sc = (part == 0) ? 0.1803368801f : 1.0f;  // 0.125*log2(e)
        #pragma unroll
        for (int m = 0; m < 4; ++m)
            #pragma unroll
            for (int n = 0; n < 4; ++n) {
                int j = j0 + wc * 64 + n * 16 + lr;
                u16x4 pkt;
                pkt[0] = f2bf(acc[m][n][0] * sc);
                pkt[1] = f2bf(acc[m][n][1] * sc);
                pkt[2] = f2bf(acc[m][n][2] * sc);
                pkt[3] = f2bf(acc[m][n][3] * sc);
                *(u16x4*)&dst[(((size_t)(b * 8 + hh)) * 1024 + j) * 64 + m * 16 + lg * 4] = pkt;
            }
    } else {
        #pragma unroll
        for (int m = 0; m < 4; ++m)
            #pragma unroll
            for (int n = 0; n < 4; ++n)
                #pragma unroll
                for (int r = 0; r < 4; ++r) {
                    int dd = m * 16 + lg * 4 + r;
                    int j = j0 + wc * 64 + n * 16 + lr;
                    vK[(((size_t)(b * 8 + hh)) * 64 + dd) * 1024 + j] = f2bf(acc[m][n][r]);
                }
    }
}

// ---------------- K4: flash attention, 4 waves x 32 q-rows, dbuf LDS --------
// One barrier per K/V tile: {barrier; write buf[(t+1)&1]; prefetch t+2;
// compute tile t from buf[t&1]}. setprio(1) around MFMA clusters.
__global__ __launch_bounds__(256, 2) void attn_kern(
    const unsigned short* __restrict__ qT, const unsigned short* __restrict__ kT,
    const unsigned short* __restrict__ vK, unsigned short* __restrict__ o_t) {
    __shared__ unsigned short k_t[2 * 64 * 72];   // [buf][j][dd]
    __shared__ unsigned short v_s[2 * 64 * 72];   // [buf][dd][j]
    __shared__ unsigned short p_s[4 * 32 * 72];   // per-wave [i][j]
    int t = threadIdx.x, w = t >> 6, l = t & 63, lr = l & 15, lg = (l >> 4) & 3;
    // XCD-chunked swizzle: 64 consecutive decoded blocks (1 bh) per XCD
    int id = blockIdx.x;
    int lin = (id & 7) * 64 + (id >> 3);
    int qt = lin & 7, bh = lin >> 3;
    int b = bh >> 3, h = bh & 7;
    const unsigned short* qb = qT + (size_t)bh * 1024 * 64;
    const unsigned short* kb = kT + (size_t)bh * 1024 * 64;
    const unsigned short* vb = vK + (size_t)bh * 64 * 1024;
    int i0 = qt * 128 + w * 32;

    // Q fragments: A[row=i][k=dd], rows i0 + it*16 + lr  (b128 loads)
    bf16x8 aq[2][2];
    #pragma unroll
    for (int it = 0; it < 2; ++it)
        #pragma unroll
        for (int kt = 0; kt < 2; ++kt)
            aq[it][kt] = *(const bf16x8*)&qb[(size_t)(i0 + it * 16 + lr) * 64 + kt * 32 + lg * 8];

    bf16x8 ones;
    #pragma unroll
    for (int e = 0; e < 8; ++e) ones[e] = (short)0x3F80;   // bf16 1.0

    float m8[2][4];
    #pragma unroll
    for (int it = 0; it < 2; ++it)
        #pragma unroll
        for (int r = 0; r < 4; ++r) m8[it][r] = -3.0e38f;
    f32x4 accO[2][4] = {};
    f32x4 accL[2] = {};
    unsigned short* pw = p_s + w * (32 * 72);

    // staging: thread t stages 32B of K and 32B of V per tile
    int srow = t >> 2, scol = (t & 3) * 16;
    const unsigned short* kg = kb + srow * 64 + scol;            // K row j=srow
    const unsigned short* vg = vb + (size_t)srow * 1024 + scol;  // V row dd=srow
    int soff = srow * 72 + scol;

    // prologue: tile 0 -> buf0 directly; tile 1 -> regs
    {
        bf16x8 a0 = *(const bf16x8*)kg, a1 = *(const bf16x8*)(kg + 8);
        bf16x8 c0 = *(const bf16x8*)vg, c1 = *(const bf16x8*)(vg + 8);
        *(bf16x8*)&k_t[soff] = a0; *(bf16x8*)&k_t[soff + 8] = a1;
        *(bf16x8*)&v_s[soff] = c0; *(bf16x8*)&v_s[soff + 8] = c1;
    }
    bf16x8 nk0 = *(const bf16x8*)(kg + 4096), nk1 = *(const bf16x8*)(kg + 4096 + 8);
    bf16x8 nv0 = *(const bf16x8*)(vg + 64),   nv1 = *(const bf16x8*)(vg + 64 + 8);

    for (int tile = 0; tile < 16; ++tile) {
        __syncthreads();                       // buf[tile&1] ready; buf[(tile+1)&1] free
        const unsigned short* kc = k_t + (tile & 1) * 4608;
        const unsigned short* vc = v_s + (tile & 1) * 4608;
        if (tile < 15) {
            unsigned short* kn = k_t + ((tile + 1) & 1) * 4608 + soff;
            unsigned short* vn = v_s + ((tile + 1) & 1) * 4608 + soff;
            *(bf16x8*)kn = nk0; *(bf16x8*)(kn + 8) = nk1;
            *(bf16x8*)vn = nv0; *(bf16x8*)(vn + 8) = nv1;
            if (tile < 14) {                   // prefetch tile+2 (hides under compute)
                const unsigned short* kp = kg + (tile + 2) * 4096;
                const unsigned short* vp = vg + (tile + 2) * 64;
                nk0 = *(const bf16x8*)kp; nk1 = *(const bf16x8*)(kp + 8);
                nv0 = *(const bf16x8*)vp; nv1 = *(const bf16x8*)(vp + 8);
            }
        }

        // S = Q K^T  (log2 domain) — bk shared by both i-tiles
        f32x4 s[2][4] = {};
        __builtin_amdgcn_s_setprio(1);
        #pragma unroll
        for (int kt = 0; kt < 2; ++kt) {
            bf16x8 bk[4];
            #pragma unroll
            for (int jt = 0; jt < 4; ++jt)
                bk[jt] = *(const bf16x8*)&kc[(jt * 16 + lr) * 72 + kt * 32 + lg * 8];
            #pragma unroll
            for (int it = 0; it < 2; ++it)
                #pragma unroll
                for (int jt = 0; jt < 4; ++jt)
                    s[it][jt] = MFMA16(aq[it][kt], bk[jt], s[it][jt]);
        }
        __builtin_amdgcn_s_setprio(0);

        // per-row tile max via DPP; defer-max: rescale only on growth
        float sm[2][4];
        float g = -3.0e38f;
        #pragma unroll
        for (int it = 0; it < 2; ++it)
            #pragma unroll
            for (int r = 0; r < 4; ++r) {
                float v0 = fmaxf(fmaxf(s[it][0][r], s[it][1][r]),
                                 fmaxf(s[it][2][r], s[it][3][r]));
                v0 = fmaxf(v0, ROR16(v0, 1));
                v0 = fmaxf(v0, ROR16(v0, 2));
                v0 = fmaxf(v0, ROR16(v0, 4));
                v0 = fmaxf(v0, ROR16(v0, 8));
                sm[it][r] = v0;
                g = fmaxf(g, v0 - m8[it][r]);
            }
        if (__any(g > 11.0f)) {
            #pragma unroll
            for (int it = 0; it < 2; ++it)
                #pragma unroll
                for (int r = 0; r < 4; ++r) {
                    float mn = fmaxf(m8[it][r], sm[it][r]);
                    float al = EXP2(m8[it][r] - mn);
                    accL[it][r] *= al;
                    #pragma unroll
                    for (int dt = 0; dt < 4; ++dt) accO[it][dt][r] *= al;
                    m8[it][r] = mn;
                }
        }

        // P = exp2(S - m), pack to bf16 in wave-private LDS
        #pragma unroll
        for (int it = 0; it < 2; ++it)
            #pragma unroll
            for (int jt = 0; jt < 4; ++jt) {
                unsigned u01 = pk2(EXP2(s[it][jt][0] - m8[it][0]),
                                   EXP2(s[it][jt][1] - m8[it][1]));
                unsigned u23 = pk2(EXP2(s[it][jt][2] - m8[it][2]),
                                   EXP2(s[it][jt][3] - m8[it][3]));
                int row = it * 16 + lg * 4;
                int col = jt * 16 + lr;
                pw[(row + 0) * 72 + col] = (unsigned short)u01;
                pw[(row + 1) * 72 + col] = (unsigned short)(u01 >> 16);
                pw[(row + 2) * 72 + col] = (unsigned short)u23;
                pw[(row + 3) * 72 + col] = (unsigned short)(u23 >> 16);
            }

        // O += P V^T ; L += P * 1  — bv shared by both i-tiles
        __builtin_amdgcn_s_setprio(1);
        #pragma unroll
        for (int kj = 0; kj < 2; ++kj) {
            bf16x8 bv[4];
            #pragma unroll
            for (int dt = 0; dt < 4; ++dt)
                bv[dt] = *(const bf16x8*)&vc[(dt * 16 + lr) * 72 + kj * 32 + lg * 8];
            #pragma unroll
            for (int it = 0; it < 2; ++it) {
                bf16x8 pa = *(const bf16x8*)&pw[(it * 16 + lr) * 72 + kj * 32 + lg * 8];
                accL[it] = MFMA16(pa, ones, accL[it]);
                #pragma unroll
                for (int dt = 0; dt < 4; ++dt)
                    accO[it][dt] = MFMA16(pa, bv[dt], accO[it][dt]);
            }
        }
        __builtin_amdgcn_s_setprio(0);
    }

    // epilogue: o_t[b][i][h*64+dd] = O[i][dd] / l
    #pragma unroll
    for (int it = 0; it < 2; ++it) {
        float inv[4];
        #pragma unroll
        for (int r = 0; r < 4; ++r) inv[r] = 1.0f / accL[it][r];
        #pragma unroll
        for (int dt = 0; dt < 4; ++dt)
            #pragma unroll
            for (int r = 0; r < 4; ++r) {
                int i = i0 + it * 16 + lg * 4 + r;
                o_t[((size_t)b * 1024 + i) * 512 + h * 64 + dt * 16 + lr] =
                    f2bf(accO[it][dt][r] * inv[r]);
            }
    }
}

// ---------------- K5: proj GEMM + bias + residual(xn) -----------------------
// Same global_load_lds staging as qkv_gemm.
__global__ __launch_bounds__(256) void proj_gemm(
    const unsigned short* __restrict__ W, const unsigned short* __restrict__ o_t,
    const float* __restrict__ b_out, const float* __restrict__ x,
    const float* __restrict__ gamma, const float* __restrict__ beta,
    const float2* __restrict__ stats, float* __restrict__ out) {
    __shared__ unsigned short a_t[128 * 64];
    __shared__ unsigned short b_t[128 * 64];
    int t = threadIdx.x, w = t >> 6, l = t & 63, lr = l & 15, lg = l >> 4;
    int jt = blockIdx.x, mt = blockIdx.y, b = blockIdx.z;
    int o0 = mt * 128, j0 = jt * 128;
    int wr = w >> 1, wc = w & 1;
    const unsigned short* Bsrc = o_t + (size_t)b * 1024 * 512;
    f32x4 acc[4][4] = {};
    const unsigned short* gA = W    + (size_t)(o0 + w * 32 + (l >> 3)) * 512 + (l & 7) * 8;
    const unsigned short* gB = Bsrc + (size_t)(j0 + w * 32 + (l >> 3)) * 512 + (l & 7) * 8;
    for (int kk = 0; kk < 512; kk += 64) {
        #pragma unroll
        for (int k = 0; k < 4; ++k) {
            glds16(gA + (size_t)k * 4096 + kk, a_t + w * 2048 + k * 512);
            glds16(gB + (size_t)k * 4096 + kk, b_t + w * 2048 + k * 512);
        }
        __syncthreads();
        __builtin_amdgcn_s_setprio(1);
        #pragma unroll
        for (int ks = 0; ks < 2; ++ks) {
            bf16x8 af[4], bfr[4];
            #pragma unroll
            for (int m = 0; m < 4; ++m)
                af[m] = *(const bf16x8*)&a_t[(wr * 64 + m * 16 + lr) * 64 + ks * 32 + lg * 8];
            #pragma unroll
            for (int n = 0; n < 4; ++n)
                bfr[n] = *(const bf16x8*)&b_t[(wc * 64 + n * 16 + lr) * 64 + ks * 32 + lg * 8];
            #pragma unroll
            for (int m = 0; m < 4; ++m)
                #pragma unroll
                for (int n = 0; n < 4; ++n)
                    acc[m][n] = MFMA16(af[m], bfr[n], acc[m][n]);
        }
        __builtin_amdgcn_s_setprio(0);
        __syncthreads();
    }
    #pragma unroll
    for (int m = 0; m < 4; ++m)
        #pragma unroll
        for (int r = 0; r < 4; ++r) {
            int o = o0 + wr * 64 + m * 16 + lg * 4 + r;
            float2 ms = stats[b * 8 + (o >> 6)];
            float g  = gamma[o] * ms.y;
            float bb = beta[o] - ms.x * g + b_out[o];
            const float* xr = x + ((size_t)b * 512 + o) * 1024;
            #pragma unroll
            for (int n = 0; n < 4; ++n) {
                int j = j0 + wc * 64 + n * 16 + lr;
                float xn = fmaf(xr[j], g, bb);
                out[((size_t)b * 512 + o) * 1024 + j] = acc[m][n][r] + xn;
            }
        }
}

// ---------------------------------------------------------------------------
extern "C" void kernel_launch(void* const* d_in, const int* in_sizes, int n_in,
                              void* d_out, int out_size, void* d_ws, size_t ws_size,
                              hipStream_t stream) {
    const float* x     = (const float*)d_in[0];
    const float* gamma = (const float*)d_in[1];
    const float* beta  = (const float*)d_in[2];
    const float* w_qkv = (const float*)d_in[3];
    const float* w_out = (const float*)d_in[4];
    const float* b_out = (const float*)d_in[5];
    float* out = (float*)d_out;

    char* ws = (char*)d_ws;
    unsigned short* wqb   = (unsigned short*)(ws);                    // 1.5 MB
    unsigned short* wob   = (unsigned short*)(ws + 0x180000);         // 0.5 MB
    float2*         stats = (float2*)(ws + 0x200000);                 // 512 B
    unsigned short* xnT   = (unsigned short*)(ws + 0x210000);         // 8 MB
    unsigned short* qT    = (unsigned short*)(ws + 0xA10000);         // 8 MB
    unsigned short* kT    = (unsigned short*)(ws + 0x1210000);        // 8 MB
    unsigned short* vK    = (unsigned short*)(ws + 0x1A10000);        // 8 MB
    unsigned short* o_t   = (unsigned short*)(ws + 0x2210000);        // 8 MB
    // total ~44.1 MB

    prep_kern<<<832, 256, 0, stream>>>(x, w_qkv, w_out, stats, wqb, wob);
    gn_norm_t<<<dim3(16, 8, 8), 256, 0, stream>>>(x, gamma, beta, stats, xnT);
    qkv_gemm<<<dim3(8, 12, 8), 256, 0, stream>>>(wqb, xnT, qT, kT, vK);
    attn_kern<<<512, 256, 0, stream>>>(qT, kT, vK, o_t);
    proj_gemm<<<dim3(8, 4, 8), 256, 0, stream>>>(wob, o_t, b_out, x, gamma, beta, stats, out);
}

// Round 15
// 89.698 us; speedup vs baseline: 1.2343x; 1.1806x over previous
//
#include <hip/hip_runtime.h>
#include <hip/hip_bf16.h>

// ---------------------------------------------------------------------------
// Fused: GroupNorm -> QKV (1x1 conv) -> 8-head attention (n=1024,d=64)
//        -> proj (1x1 conv) + bias + residual(xn)
// b=8, c=512, n=1024, GROUPS=8, HEADS=8, dim_head=64. bf16 MFMA, fp32 accum.
// R15: stats split into 512 partial-reduce blocks (was 64 -> grid-starved,
//      ~10.7us serial streaming); gn_norm_t finalizes from partials and
//      publishes stats for proj. GEMMs/attention identical to R14 (best).
// ---------------------------------------------------------------------------

typedef short bf16x8 __attribute__((ext_vector_type(8)));
typedef float f32x4 __attribute__((ext_vector_type(4)));
typedef unsigned short u16x4 __attribute__((ext_vector_type(4)));

#define MFMA16(a, b, c) __builtin_amdgcn_mfma_f32_16x16x32_bf16(a, b, c, 0, 0, 0)
#define EXP2(x) __builtin_amdgcn_exp2f(x)
// rotate-right by N within each 16-lane row (pure VALU DPP)
#define ROR16(v, N) __int_as_float(__builtin_amdgcn_mov_dpp(__float_as_int(v), 0x120 + (N), 0xF, 0xF, false))

__device__ __forceinline__ unsigned short f2bf(float f) {
    unsigned u = __float_as_uint(f);
    u += 0x7fffu + ((u >> 16) & 1u);   // round-to-nearest-even
    return (unsigned short)(u >> 16);
}

// pack two fp32 -> u32 of two bf16 (lo=a, hi=b), RNE via HIP intrinsic
__device__ __forceinline__ unsigned pk2(float a, float b) {
    __hip_bfloat162 h = __float22bfloat162_rn(float2{a, b});
    unsigned r;
    __builtin_memcpy(&r, &h, 4);
    return r;
}

// async global -> LDS, 16B per lane; lptr must be wave-uniform (HW adds lane*16)
__device__ __forceinline__ void glds16(const unsigned short* g, unsigned short* l) {
    __builtin_amdgcn_global_load_lds(
        (const __attribute__((address_space(1))) unsigned int*)g,
        (__attribute__((address_space(3))) unsigned int*)l, 16, 0, 0);
}

// ---------------- K0: stats partials (512 blocks) + weight cvt (768) --------
// blocks 0..511: partial (sum, sumsq) over a 32KB chunk: bg = blk>>3, chunk
// = blk&7. blocks 512..1279: weight bf16 conversion.
__global__ __launch_bounds__(256) void prep_kern(
    const float* __restrict__ x, const float* __restrict__ wq,
    const float* __restrict__ wo, float2* __restrict__ partials,
    unsigned short* __restrict__ wqb, unsigned short* __restrict__ wob) {
    int blk = blockIdx.x, t = threadIdx.x;
    if (blk < 512) {
        __shared__ float ss[256], sq[256];
        int bg = blk >> 3, chunk = blk & 7;
        const float4* p = reinterpret_cast<const float4*>(
            x + (size_t)bg * 65536 + chunk * 8192);
        float s = 0.f, q = 0.f;
        #pragma unroll
        for (int i = 0; i < 8; ++i) {
            float4 v = p[t + i * 256];
            s += v.x + v.y + v.z + v.w;
            q += v.x * v.x + v.y * v.y + v.z * v.z + v.w * v.w;
        }
        ss[t] = s; sq[t] = q; __syncthreads();
        for (int o = 128; o > 0; o >>= 1) {
            if (t < o) { ss[t] += ss[t + o]; sq[t] += sq[t + o]; }
            __syncthreads();
        }
        if (t == 0) partials[blk] = make_float2(ss[0], sq[0]);
    } else {
        int i = (blk - 512) * 256 + t;        // 0..196607
        {
            float4 v = reinterpret_cast<const float4*>(wq)[i];
            unsigned short* d = wqb + (size_t)i * 4;
            d[0] = f2bf(v.x); d[1] = f2bf(v.y); d[2] = f2bf(v.z); d[3] = f2bf(v.w);
        }
        if (i < 65536) {
            float4 v = reinterpret_cast<const float4*>(wo)[i];
            unsigned short* d = wob + (size_t)i * 4;
            d[0] = f2bf(v.x); d[1] = f2bf(v.y); d[2] = f2bf(v.z); d[3] = f2bf(v.w);
        }
    }
}

// ---------------- K2: normalize + transpose -> xnT[b][n][c] bf16 ------------
// Finalizes group stats from the 8 partials (redundantly per block, cheap);
// jt==0 blocks publish stats[] for proj_gemm's epilogue.
__global__ __launch_bounds__(256) void gn_norm_t(
    const float* __restrict__ x, const float* __restrict__ gamma,
    const float* __restrict__ beta, const float2* __restrict__ partials,
    float2* __restrict__ stats, unsigned short* __restrict__ xnT) {
    __shared__ unsigned short tile[64 * 72];
    int t = threadIdx.x;
    int jt = blockIdx.x, ct = blockIdx.y, b = blockIdx.z;
    float s = 0.f, q = 0.f;
    #pragma unroll
    for (int k = 0; k < 8; ++k) {
        float2 p = partials[(b * 8 + ct) * 8 + k];
        s += p.x; q += p.y;
    }
    float mean = s * (1.f / 65536.f);
    float var  = q * (1.f / 65536.f) - mean * mean;
    float rstd = rsqrtf(var + 1e-5f);
    if (jt == 0 && t == 0) stats[b * 8 + ct] = make_float2(mean, rstd);
    int c = t >> 2, jseg = (t & 3) * 16;
    int ch = ct * 64 + c;
    float g  = gamma[ch] * rstd;
    float bb = beta[ch] - mean * g;
    const float* src = x + ((size_t)(b * 512 + ch)) * 1024 + jt * 64 + jseg;
    float4 v0 = *(const float4*)(src);
    float4 v1 = *(const float4*)(src + 4);
    float4 v2 = *(const float4*)(src + 8);
    float4 v3 = *(const float4*)(src + 12);
    float vv[16] = {v0.x,v0.y,v0.z,v0.w, v1.x,v1.y,v1.z,v1.w,
                    v2.x,v2.y,v2.z,v2.w, v3.x,v3.y,v3.z,v3.w};
    #pragma unroll
    for (int e = 0; e < 16; ++e)
        tile[(jseg + e) * 72 + c] = f2bf(fmaf(vv[e], g, bb));
    __syncthreads();
    int j = t >> 2, cseg = (t & 3) * 16;
    unsigned short* dst = xnT + ((size_t)b * 1024 + jt * 64 + j) * 512 + ct * 64 + cseg;
    bf16x8 a0 = *(const bf16x8*)&tile[j * 72 + cseg];
    bf16x8 a1 = *(const bf16x8*)&tile[j * 72 + cseg + 8];
    *(bf16x8*)dst = a0;
    *(bf16x8*)(dst + 8) = a1;
}

// ---------------- K3: QKV GEMM -> qT (scaled), kT, v ------------------------
// A = Wqkv bf16 [1536][512] row-major; B = xnT[b] [1024 j][512 c] row-major.
// qT,kT: [b*8+h][i/j][dd]  (dd contiguous);  v: [b*8+h][dd][j].
// Q pre-scaled by 0.125 * log2(e) so attention softmax runs in exp2 domain.
// Staging via global_load_lds into LINEAR LDS tiles (m97 pattern).
__global__ __launch_bounds__(256) void qkv_gemm(
    const unsigned short* __restrict__ W, const unsigned short* __restrict__ xnT,
    unsigned short* __restrict__ qT, unsigned short* __restrict__ kT,
    unsigned short* __restrict__ vK) {
    __shared__ unsigned short a_t[128 * 64];   // [o][k] linear
    __shared__ unsigned short b_t[128 * 64];   // [j][k] linear
    int t = threadIdx.x, w = t >> 6, l = t & 63, lr = l & 15, lg = l >> 4;
    int jt = blockIdx.x, mt = blockIdx.y, b = blockIdx.z;
    int o0 = mt * 128, j0 = jt * 128;
    int wr = w >> 1, wc = w & 1;
    const unsigned short* Bsrc = xnT + (size_t)b * 1024 * 512;
    f32x4 acc[4][4] = {};
    // glds source: lane l covers row w*32 + k*8 + (l>>3), cols (l&7)*8..+7
    const unsigned short* gA = W    + (size_t)(o0 + w * 32 + (l >> 3)) * 512 + (l & 7) * 8;
    const unsigned short* gB = Bsrc + (size_t)(j0 + w * 32 + (l >> 3)) * 512 + (l & 7) * 8;
    for (int kk = 0; kk < 512; kk += 64) {
        #pragma unroll
        for (int k = 0; k < 4; ++k) {
            glds16(gA + (size_t)k * 4096 + kk, a_t + w * 2048 + k * 512);
            glds16(gB + (size_t)k * 4096 + kk, b_t + w * 2048 + k * 512);
        }
        __syncthreads();                       // drains vmcnt -> LDS filled
        __builtin_amdgcn_s_setprio(1);
        #pragma unroll
        for (int ks = 0; ks < 2; ++ks) {
            bf16x8 af[4], bfr[4];
            #pragma unroll
            for (int m = 0; m < 4; ++m)
                af[m] = *(const bf16x8*)&a_t[(wr * 64 + m * 16 + lr) * 64 + ks * 32 + lg * 8];
            #pragma unroll
            for (int n = 0; n < 4; ++n)
                bfr[n] = *(const bf16x8*)&b_t[(wc * 64 + n * 16 + lr) * 64 + ks * 32 + lg * 8];
            #pragma unroll
            for (int m = 0; m < 4; ++m)
                #pragma unroll
                for (int n = 0; n < 4; ++n)
                    acc[m][n] = MFMA16(af[m], bfr[n], acc[m][n]);
        }
        __builtin_amdgcn_s_setprio(0);
        __syncthreads();                       // all reads done before next glds
    }
    int part = mt >> 2;                       // 0=q, 1=k, 2=v
    int hh = ((mt * 2) + wr) & 7;             // head for this wave-row half
    if (part < 2) {
        unsigned short* dst = (part == 0) ? qT : kT;
        float sc = (part == 0) ? 0.1803368801f : 1.0f;  // 0.125*log2(e)
        #pragma unroll
        for (int m = 0; m < 4; ++m)
            #pragma unroll
            for (int n = 0; n < 4; ++n) {
                int j = j0 + wc * 64 + n * 16 + lr;
                u16x4 pkt;
                pkt[0] = f2bf(acc[m][n][0] * sc);
                pkt[1] = f2bf(acc[m][n][1] * sc);
                pkt[2] = f2bf(acc[m][n][2] * sc);
                pkt[3] = f2bf(acc[m][n][3] * sc);
                *(u16x4*)&dst[(((size_t)(b * 8 + hh)) * 1024 + j) * 64 + m * 16 + lg * 4] = pkt;
            }
    } else {
        #pragma unroll
        for (int m = 0; m < 4; ++m)
            #pragma unroll
            for (int n = 0; n < 4; ++n)
                #pragma unroll
                for (int r = 0; r < 4; ++r) {
                    int dd = m * 16 + lg * 4 + r;
                    int j = j0 + wc * 64 + n * 16 + lr;
                    vK[(((size_t)(b * 8 + hh)) * 64 + dd) * 1024 + j] = f2bf(acc[m][n][r]);
                }
    }
}

// ---------------- K4: flash attention, 4 waves x 32 q-rows, dbuf LDS --------
// One barrier per K/V tile: {barrier; write buf[(t+1)&1]; prefetch t+2;
// compute tile t from buf[t&1]}. setprio(1) around MFMA clusters.
__global__ __launch_bounds__(256, 2) void attn_kern(
    const unsigned short* __restrict__ qT, const unsigned short* __restrict__ kT,
    const unsigned short* __restrict__ vK, unsigned short* __restrict__ o_t) {
    __shared__ unsigned short k_t[2 * 64 * 72];   // [buf][j][dd]
    __shared__ unsigned short v_s[2 * 64 * 72];   // [buf][dd][j]
    __shared__ unsigned short p_s[4 * 32 * 72];   // per-wave [i][j]
    int t = threadIdx.x, w = t >> 6, l = t & 63, lr = l & 15, lg = (l >> 4) & 3;
    // XCD-chunked swizzle: 64 consecutive decoded blocks (1 bh) per XCD
    int id = blockIdx.x;
    int lin = (id & 7) * 64 + (id >> 3);
    int qt = lin & 7, bh = lin >> 3;
    int b = bh >> 3, h = bh & 7;
    const unsigned short* qb = qT + (size_t)bh * 1024 * 64;
    const unsigned short* kb = kT + (size_t)bh * 1024 * 64;
    const unsigned short* vb = vK + (size_t)bh * 64 * 1024;
    int i0 = qt * 128 + w * 32;

    // Q fragments: A[row=i][k=dd], rows i0 + it*16 + lr  (b128 loads)
    bf16x8 aq[2][2];
    #pragma unroll
    for (int it = 0; it < 2; ++it)
        #pragma unroll
        for (int kt = 0; kt < 2; ++kt)
            aq[it][kt] = *(const bf16x8*)&qb[(size_t)(i0 + it * 16 + lr) * 64 + kt * 32 + lg * 8];

    bf16x8 ones;
    #pragma unroll
    for (int e = 0; e < 8; ++e) ones[e] = (short)0x3F80;   // bf16 1.0

    float m8[2][4];
    #pragma unroll
    for (int it = 0; it < 2; ++it)
        #pragma unroll
        for (int r = 0; r < 4; ++r) m8[it][r] = -3.0e38f;
    f32x4 accO[2][4] = {};
    f32x4 accL[2] = {};
    unsigned short* pw = p_s + w * (32 * 72);

    // staging: thread t stages 32B of K and 32B of V per tile
    int srow = t >> 2, scol = (t & 3) * 16;
    const unsigned short* kg = kb + srow * 64 + scol;            // K row j=srow
    const unsigned short* vg = vb + (size_t)srow * 1024 + scol;  // V row dd=srow
    int soff = srow * 72 + scol;

    // prologue: tile 0 -> buf0 directly; tile 1 -> regs
    {
        bf16x8 a0 = *(const bf16x8*)kg, a1 = *(const bf16x8*)(kg + 8);
        bf16x8 c0 = *(const bf16x8*)vg, c1 = *(const bf16x8*)(vg + 8);
        *(bf16x8*)&k_t[soff] = a0; *(bf16x8*)&k_t[soff + 8] = a1;
        *(bf16x8*)&v_s[soff] = c0; *(bf16x8*)&v_s[soff + 8] = c1;
    }
    bf16x8 nk0 = *(const bf16x8*)(kg + 4096), nk1 = *(const bf16x8*)(kg + 4096 + 8);
    bf16x8 nv0 = *(const bf16x8*)(vg + 64),   nv1 = *(const bf16x8*)(vg + 64 + 8);

    for (int tile = 0; tile < 16; ++tile) {
        __syncthreads();                       // buf[tile&1] ready; buf[(tile+1)&1] free
        const unsigned short* kc = k_t + (tile & 1) * 4608;
        const unsigned short* vc = v_s + (tile & 1) * 4608;
        if (tile < 15) {
            unsigned short* kn = k_t + ((tile + 1) & 1) * 4608 + soff;
            unsigned short* vn = v_s + ((tile + 1) & 1) * 4608 + soff;
            *(bf16x8*)kn = nk0; *(bf16x8*)(kn + 8) = nk1;
            *(bf16x8*)vn = nv0; *(bf16x8*)(vn + 8) = nv1;
            if (tile < 14) {                   // prefetch tile+2 (hides under compute)
                const unsigned short* kp = kg + (tile + 2) * 4096;
                const unsigned short* vp = vg + (tile + 2) * 64;
                nk0 = *(const bf16x8*)kp; nk1 = *(const bf16x8*)(kp + 8);
                nv0 = *(const bf16x8*)vp; nv1 = *(const bf16x8*)(vp + 8);
            }
        }

        // S = Q K^T  (log2 domain) — bk shared by both i-tiles
        f32x4 s[2][4] = {};
        __builtin_amdgcn_s_setprio(1);
        #pragma unroll
        for (int kt = 0; kt < 2; ++kt) {
            bf16x8 bk[4];
            #pragma unroll
            for (int jt = 0; jt < 4; ++jt)
                bk[jt] = *(const bf16x8*)&kc[(jt * 16 + lr) * 72 + kt * 32 + lg * 8];
            #pragma unroll
            for (int it = 0; it < 2; ++it)
                #pragma unroll
                for (int jt = 0; jt < 4; ++jt)
                    s[it][jt] = MFMA16(aq[it][kt], bk[jt], s[it][jt]);
        }
        __builtin_amdgcn_s_setprio(0);

        // per-row tile max via DPP; defer-max: rescale only on growth
        float sm[2][4];
        float g = -3.0e38f;
        #pragma unroll
        for (int it = 0; it < 2; ++it)
            #pragma unroll
            for (int r = 0; r < 4; ++r) {
                float v0 = fmaxf(fmaxf(s[it][0][r], s[it][1][r]),
                                 fmaxf(s[it][2][r], s[it][3][r]));
                v0 = fmaxf(v0, ROR16(v0, 1));
                v0 = fmaxf(v0, ROR16(v0, 2));
                v0 = fmaxf(v0, ROR16(v0, 4));
                v0 = fmaxf(v0, ROR16(v0, 8));
                sm[it][r] = v0;
                g = fmaxf(g, v0 - m8[it][r]);
            }
        if (__any(g > 11.0f)) {
            #pragma unroll
            for (int it = 0; it < 2; ++it)
                #pragma unroll
                for (int r = 0; r < 4; ++r) {
                    float mn = fmaxf(m8[it][r], sm[it][r]);
                    float al = EXP2(m8[it][r] - mn);
                    accL[it][r] *= al;
                    #pragma unroll
                    for (int dt = 0; dt < 4; ++dt) accO[it][dt][r] *= al;
                    m8[it][r] = mn;
                }
        }

        // P = exp2(S - m), pack to bf16 in wave-private LDS
        #pragma unroll
        for (int it = 0; it < 2; ++it)
            #pragma unroll
            for (int jt = 0; jt < 4; ++jt) {
                unsigned u01 = pk2(EXP2(s[it][jt][0] - m8[it][0]),
                                   EXP2(s[it][jt][1] - m8[it][1]));
                unsigned u23 = pk2(EXP2(s[it][jt][2] - m8[it][2]),
                                   EXP2(s[it][jt][3] - m8[it][3]));
                int row = it * 16 + lg * 4;
                int col = jt * 16 + lr;
                pw[(row + 0) * 72 + col] = (unsigned short)u01;
                pw[(row + 1) * 72 + col] = (unsigned short)(u01 >> 16);
                pw[(row + 2) * 72 + col] = (unsigned short)u23;
                pw[(row + 3) * 72 + col] = (unsigned short)(u23 >> 16);
            }

        // O += P V^T ; L += P * 1  — bv shared by both i-tiles
        __builtin_amdgcn_s_setprio(1);
        #pragma unroll
        for (int kj = 0; kj < 2; ++kj) {
            bf16x8 bv[4];
            #pragma unroll
            for (int dt = 0; dt < 4; ++dt)
                bv[dt] = *(const bf16x8*)&vc[(dt * 16 + lr) * 72 + kj * 32 + lg * 8];
            #pragma unroll
            for (int it = 0; it < 2; ++it) {
                bf16x8 pa = *(const bf16x8*)&pw[(it * 16 + lr) * 72 + kj * 32 + lg * 8];
                accL[it] = MFMA16(pa, ones, accL[it]);
                #pragma unroll
                for (int dt = 0; dt < 4; ++dt)
                    accO[it][dt] = MFMA16(pa, bv[dt], accO[it][dt]);
            }
        }
        __builtin_amdgcn_s_setprio(0);
    }

    // epilogue: o_t[b][i][h*64+dd] = O[i][dd] / l
    #pragma unroll
    for (int it = 0; it < 2; ++it) {
        float inv[4];
        #pragma unroll
        for (int r = 0; r < 4; ++r) inv[r] = 1.0f / accL[it][r];
        #pragma unroll
        for (int dt = 0; dt < 4; ++dt)
            #pragma unroll
            for (int r = 0; r < 4; ++r) {
                int i = i0 + it * 16 + lg * 4 + r;
                o_t[((size_t)b * 1024 + i) * 512 + h * 64 + dt * 16 + lr] =
                    f2bf(accO[it][dt][r] * inv[r]);
            }
    }
}

// ---------------- K5: proj GEMM + bias + residual(xn) -----------------------
// Same global_load_lds staging as qkv_gemm.
__global__ __launch_bounds__(256) void proj_gemm(
    const unsigned short* __restrict__ W, const unsigned short* __restrict__ o_t,
    const float* __restrict__ b_out, const float* __restrict__ x,
    const float* __restrict__ gamma, const float* __restrict__ beta,
    const float2* __restrict__ stats, float* __restrict__ out) {
    __shared__ unsigned short a_t[128 * 64];
    __shared__ unsigned short b_t[128 * 64];
    int t = threadIdx.x, w = t >> 6, l = t & 63, lr = l & 15, lg = l >> 4;
    int jt = blockIdx.x, mt = blockIdx.y, b = blockIdx.z;
    int o0 = mt * 128, j0 = jt * 128;
    int wr = w >> 1, wc = w & 1;
    const unsigned short* Bsrc = o_t + (size_t)b * 1024 * 512;
    f32x4 acc[4][4] = {};
    const unsigned short* gA = W    + (size_t)(o0 + w * 32 + (l >> 3)) * 512 + (l & 7) * 8;
    const unsigned short* gB = Bsrc + (size_t)(j0 + w * 32 + (l >> 3)) * 512 + (l & 7) * 8;
    for (int kk = 0; kk < 512; kk += 64) {
        #pragma unroll
        for (int k = 0; k < 4; ++k) {
            glds16(gA + (size_t)k * 4096 + kk, a_t + w * 2048 + k * 512);
            glds16(gB + (size_t)k * 4096 + kk, b_t + w * 2048 + k * 512);
        }
        __syncthreads();
        __builtin_amdgcn_s_setprio(1);
        #pragma unroll
        for (int ks = 0; ks < 2; ++ks) {
            bf16x8 af[4], bfr[4];
            #pragma unroll
            for (int m = 0; m < 4; ++m)
                af[m] = *(const bf16x8*)&a_t[(wr * 64 + m * 16 + lr) * 64 + ks * 32 + lg * 8];
            #pragma unroll
            for (int n = 0; n < 4; ++n)
                bfr[n] = *(const bf16x8*)&b_t[(wc * 64 + n * 16 + lr) * 64 + ks * 32 + lg * 8];
            #pragma unroll
            for (int m = 0; m < 4; ++m)
                #pragma unroll
                for (int n = 0; n < 4; ++n)
                    acc[m][n] = MFMA16(af[m], bfr[n], acc[m][n]);
        }
        __builtin_amdgcn_s_setprio(0);
        __syncthreads();
    }
    #pragma unroll
    for (int m = 0; m < 4; ++m)
        #pragma unroll
        for (int r = 0; r < 4; ++r) {
            int o = o0 + wr * 64 + m * 16 + lg * 4 + r;
            float2 ms = stats[b * 8 + (o >> 6)];
            float g  = gamma[o] * ms.y;
            float bb = beta[o] - ms.x * g + b_out[o];
            const float* xr = x + ((size_t)b * 512 + o) * 1024;
            #pragma unroll
            for (int n = 0; n < 4; ++n) {
                int j = j0 + wc * 64 + n * 16 + lr;
                float xn = fmaf(xr[j], g, bb);
                out[((size_t)b * 512 + o) * 1024 + j] = acc[m][n][r] + xn;
            }
        }
}

// ---------------------------------------------------------------------------
extern "C" void kernel_launch(void* const* d_in, const int* in_sizes, int n_in,
                              void* d_out, int out_size, void* d_ws, size_t ws_size,
                              hipStream_t stream) {
    const float* x     = (const float*)d_in[0];
    const float* gamma = (const float*)d_in[1];
    const float* beta  = (const float*)d_in[2];
    const float* w_qkv = (const float*)d_in[3];
    const float* w_out = (const float*)d_in[4];
    const float* b_out = (const float*)d_in[5];
    float* out = (float*)d_out;

    char* ws = (char*)d_ws;
    unsigned short* wqb     = (unsigned short*)(ws);                  // 1.5 MB
    unsigned short* wob     = (unsigned short*)(ws + 0x180000);       // 0.5 MB
    float2*         stats   = (float2*)(ws + 0x200000);               // 512 B
    float2*         partial = (float2*)(ws + 0x201000);               // 4 KB
    unsigned short* xnT     = (unsigned short*)(ws + 0x210000);       // 8 MB
    unsigned short* qT      = (unsigned short*)(ws + 0xA10000);       // 8 MB
    unsigned short* kT      = (unsigned short*)(ws + 0x1210000);      // 8 MB
    unsigned short* vK      = (unsigned short*)(ws + 0x1A10000);      // 8 MB
    unsigned short* o_t     = (unsigned short*)(ws + 0x2210000);      // 8 MB
    // total ~44.1 MB

    prep_kern<<<1280, 256, 0, stream>>>(x, w_qkv, w_out, partial, wqb, wob);
    gn_norm_t<<<dim3(16, 8, 8), 256, 0, stream>>>(x, gamma, beta, partial, stats, xnT);
    qkv_gemm<<<dim3(8, 12, 8), 256, 0, stream>>>(wqb, xnT, qT, kT, vK);
    attn_kern<<<512, 256, 0, stream>>>(qT, kT, vK, o_t);
    proj_gemm<<<dim3(8, 4, 8), 256, 0, stream>>>(wob, o_t, b_out, x, gamma, beta, stats, out);
}

// Round 16
// 86.473 us; speedup vs baseline: 1.2803x; 1.0373x over previous
//
#include <hip/hip_runtime.h>
#include <hip/hip_bf16.h>

// ---------------------------------------------------------------------------
// Fused: GroupNorm -> QKV (1x1 conv) -> 8-head attention (n=1024,d=64)
//        -> proj (1x1 conv) + bias + residual(xn)
// b=8, c=512, n=1024, GROUPS=8, HEADS=8, dim_head=64. bf16 MFMA, fp32 accum.
// R16: proj_gemm re-tiled 128x64 (grid 512 -> 2 blocks/CU, was 1 -> exposed
//      barrier drains); attn staging ds_writes moved after QK MFMA (LDS pipe
//      order). prep/gn_norm/qkv identical to R15.
// ---------------------------------------------------------------------------

typedef short bf16x8 __attribute__((ext_vector_type(8)));
typedef float f32x4 __attribute__((ext_vector_type(4)));
typedef unsigned short u16x4 __attribute__((ext_vector_type(4)));

#define MFMA16(a, b, c) __builtin_amdgcn_mfma_f32_16x16x32_bf16(a, b, c, 0, 0, 0)
#define EXP2(x) __builtin_amdgcn_exp2f(x)
// rotate-right by N within each 16-lane row (pure VALU DPP)
#define ROR16(v, N) __int_as_float(__builtin_amdgcn_mov_dpp(__float_as_int(v), 0x120 + (N), 0xF, 0xF, false))

__device__ __forceinline__ unsigned short f2bf(float f) {
    unsigned u = __float_as_uint(f);
    u += 0x7fffu + ((u >> 16) & 1u);   // round-to-nearest-even
    return (unsigned short)(u >> 16);
}

// pack two fp32 -> u32 of two bf16 (lo=a, hi=b), RNE via HIP intrinsic
__device__ __forceinline__ unsigned pk2(float a, float b) {
    __hip_bfloat162 h = __float22bfloat162_rn(float2{a, b});
    unsigned r;
    __builtin_memcpy(&r, &h, 4);
    return r;
}

// async global -> LDS, 16B per lane; lptr must be wave-uniform (HW adds lane*16)
__device__ __forceinline__ void glds16(const unsigned short* g, unsigned short* l) {
    __builtin_amdgcn_global_load_lds(
        (const __attribute__((address_space(1))) unsigned int*)g,
        (__attribute__((address_space(3))) unsigned int*)l, 16, 0, 0);
}

// ---------------- K0: stats partials (512 blocks) + weight cvt (768) --------
__global__ __launch_bounds__(256) void prep_kern(
    const float* __restrict__ x, const float* __restrict__ wq,
    const float* __restrict__ wo, float2* __restrict__ partials,
    unsigned short* __restrict__ wqb, unsigned short* __restrict__ wob) {
    int blk = blockIdx.x, t = threadIdx.x;
    if (blk < 512) {
        __shared__ float ss[256], sq[256];
        int bg = blk >> 3, chunk = blk & 7;
        const float4* p = reinterpret_cast<const float4*>(
            x + (size_t)bg * 65536 + chunk * 8192);
        float s = 0.f, q = 0.f;
        #pragma unroll
        for (int i = 0; i < 8; ++i) {
            float4 v = p[t + i * 256];
            s += v.x + v.y + v.z + v.w;
            q += v.x * v.x + v.y * v.y + v.z * v.z + v.w * v.w;
        }
        ss[t] = s; sq[t] = q; __syncthreads();
        for (int o = 128; o > 0; o >>= 1) {
            if (t < o) { ss[t] += ss[t + o]; sq[t] += sq[t + o]; }
            __syncthreads();
        }
        if (t == 0) partials[blk] = make_float2(ss[0], sq[0]);
    } else {
        int i = (blk - 512) * 256 + t;        // 0..196607
        {
            float4 v = reinterpret_cast<const float4*>(wq)[i];
            unsigned short* d = wqb + (size_t)i * 4;
            d[0] = f2bf(v.x); d[1] = f2bf(v.y); d[2] = f2bf(v.z); d[3] = f2bf(v.w);
        }
        if (i < 65536) {
            float4 v = reinterpret_cast<const float4*>(wo)[i];
            unsigned short* d = wob + (size_t)i * 4;
            d[0] = f2bf(v.x); d[1] = f2bf(v.y); d[2] = f2bf(v.z); d[3] = f2bf(v.w);
        }
    }
}

// ---------------- K2: normalize + transpose -> xnT[b][n][c] bf16 ------------
__global__ __launch_bounds__(256) void gn_norm_t(
    const float* __restrict__ x, const float* __restrict__ gamma,
    const float* __restrict__ beta, const float2* __restrict__ partials,
    float2* __restrict__ stats, unsigned short* __restrict__ xnT) {
    __shared__ unsigned short tile[64 * 72];
    int t = threadIdx.x;
    int jt = blockIdx.x, ct = blockIdx.y, b = blockIdx.z;
    float s = 0.f, q = 0.f;
    #pragma unroll
    for (int k = 0; k < 8; ++k) {
        float2 p = partials[(b * 8 + ct) * 8 + k];
        s += p.x; q += p.y;
    }
    float mean = s * (1.f / 65536.f);
    float var  = q * (1.f / 65536.f) - mean * mean;
    float rstd = rsqrtf(var + 1e-5f);
    if (jt == 0 && t == 0) stats[b * 8 + ct] = make_float2(mean, rstd);
    int c = t >> 2, jseg = (t & 3) * 16;
    int ch = ct * 64 + c;
    float g  = gamma[ch] * rstd;
    float bb = beta[ch] - mean * g;
    const float* src = x + ((size_t)(b * 512 + ch)) * 1024 + jt * 64 + jseg;
    float4 v0 = *(const float4*)(src);
    float4 v1 = *(const float4*)(src + 4);
    float4 v2 = *(const float4*)(src + 8);
    float4 v3 = *(const float4*)(src + 12);
    float vv[16] = {v0.x,v0.y,v0.z,v0.w, v1.x,v1.y,v1.z,v1.w,
                    v2.x,v2.y,v2.z,v2.w, v3.x,v3.y,v3.z,v3.w};
    #pragma unroll
    for (int e = 0; e < 16; ++e)
        tile[(jseg + e) * 72 + c] = f2bf(fmaf(vv[e], g, bb));
    __syncthreads();
    int j = t >> 2, cseg = (t & 3) * 16;
    unsigned short* dst = xnT + ((size_t)b * 1024 + jt * 64 + j) * 512 + ct * 64 + cseg;
    bf16x8 a0 = *(const bf16x8*)&tile[j * 72 + cseg];
    bf16x8 a1 = *(const bf16x8*)&tile[j * 72 + cseg + 8];
    *(bf16x8*)dst = a0;
    *(bf16x8*)(dst + 8) = a1;
}

// ---------------- K3: QKV GEMM -> qT (scaled), kT, v ------------------------
// Staging via global_load_lds into LINEAR LDS tiles (m97 pattern).
__global__ __launch_bounds__(256) void qkv_gemm(
    const unsigned short* __restrict__ W, const unsigned short* __restrict__ xnT,
    unsigned short* __restrict__ qT, unsigned short* __restrict__ kT,
    unsigned short* __restrict__ vK) {
    __shared__ unsigned short a_t[128 * 64];   // [o][k] linear
    __shared__ unsigned short b_t[128 * 64];   // [j][k] linear
    int t = threadIdx.x, w = t >> 6, l = t & 63, lr = l & 15, lg = l >> 4;
    int jt = blockIdx.x, mt = blockIdx.y, b = blockIdx.z;
    int o0 = mt * 128, j0 = jt * 128;
    int wr = w >> 1, wc = w & 1;
    const unsigned short* Bsrc = xnT + (size_t)b * 1024 * 512;
    f32x4 acc[4][4] = {};
    const unsigned short* gA = W    + (size_t)(o0 + w * 32 + (l >> 3)) * 512 + (l & 7) * 8;
    const unsigned short* gB = Bsrc + (size_t)(j0 + w * 32 + (l >> 3)) * 512 + (l & 7) * 8;
    for (int kk = 0; kk < 512; kk += 64) {
        #pragma unroll
        for (int k = 0; k < 4; ++k) {
            glds16(gA + (size_t)k * 4096 + kk, a_t + w * 2048 + k * 512);
            glds16(gB + (size_t)k * 4096 + kk, b_t + w * 2048 + k * 512);
        }
        __syncthreads();                       // drains vmcnt -> LDS filled
        __builtin_amdgcn_s_setprio(1);
        #pragma unroll
        for (int ks = 0; ks < 2; ++ks) {
            bf16x8 af[4], bfr[4];
            #pragma unroll
            for (int m = 0; m < 4; ++m)
                af[m] = *(const bf16x8*)&a_t[(wr * 64 + m * 16 + lr) * 64 + ks * 32 + lg * 8];
            #pragma unroll
            for (int n = 0; n < 4; ++n)
                bfr[n] = *(const bf16x8*)&b_t[(wc * 64 + n * 16 + lr) * 64 + ks * 32 + lg * 8];
            #pragma unroll
            for (int m = 0; m < 4; ++m)
                #pragma unroll
                for (int n = 0; n < 4; ++n)
                    acc[m][n] = MFMA16(af[m], bfr[n], acc[m][n]);
        }
        __builtin_amdgcn_s_setprio(0);
        __syncthreads();                       // all reads done before next glds
    }
    int part = mt >> 2;                       // 0=q, 1=k, 2=v
    int hh = ((mt * 2) + wr) & 7;             // head for this wave-row half
    if (part < 2) {
        unsigned short* dst = (part == 0) ? qT : kT;
        float sc = (part == 0) ? 0.1803368801f : 1.0f;  // 0.125*log2(e)
        #pragma unroll
        for (int m = 0; m < 4; ++m)
            #pragma unroll
            for (int n = 0; n < 4; ++n) {
                int j = j0 + wc * 64 + n * 16 + lr;
                u16x4 pkt;
                pkt[0] = f2bf(acc[m][n][0] * sc);
                pkt[1] = f2bf(acc[m][n][1] * sc);
                pkt[2] = f2bf(acc[m][n][2] * sc);
                pkt[3] = f2bf(acc[m][n][3] * sc);
                *(u16x4*)&dst[(((size_t)(b * 8 + hh)) * 1024 + j) * 64 + m * 16 + lg * 4] = pkt;
            }
    } else {
        #pragma unroll
        for (int m = 0; m < 4; ++m)
            #pragma unroll
            for (int n = 0; n < 4; ++n)
                #pragma unroll
                for (int r = 0; r < 4; ++r) {
                    int dd = m * 16 + lg * 4 + r;
                    int j = j0 + wc * 64 + n * 16 + lr;
                    vK[(((size_t)(b * 8 + hh)) * 64 + dd) * 1024 + j] = f2bf(acc[m][n][r]);
                }
    }
}

// ---------------- K4: flash attention, 4 waves x 32 q-rows, dbuf LDS --------
// Order per tile: barrier -> QK MFMA -> ds_write(t+1) -> prefetch(t+2)
// -> softmax -> P pack -> PV. Writes target the other buffer (race-free).
__global__ __launch_bounds__(256, 2) void attn_kern(
    const unsigned short* __restrict__ qT, const unsigned short* __restrict__ kT,
    const unsigned short* __restrict__ vK, unsigned short* __restrict__ o_t) {
    __shared__ unsigned short k_t[2 * 64 * 72];   // [buf][j][dd]
    __shared__ unsigned short v_s[2 * 64 * 72];   // [buf][dd][j]
    __shared__ unsigned short p_s[4 * 32 * 72];   // per-wave [i][j]
    int t = threadIdx.x, w = t >> 6, l = t & 63, lr = l & 15, lg = (l >> 4) & 3;
    // XCD-chunked swizzle: 64 consecutive decoded blocks (1 bh) per XCD
    int id = blockIdx.x;
    int lin = (id & 7) * 64 + (id >> 3);
    int qt = lin & 7, bh = lin >> 3;
    int b = bh >> 3, h = bh & 7;
    const unsigned short* qb = qT + (size_t)bh * 1024 * 64;
    const unsigned short* kb = kT + (size_t)bh * 1024 * 64;
    const unsigned short* vb = vK + (size_t)bh * 64 * 1024;
    int i0 = qt * 128 + w * 32;

    // Q fragments: A[row=i][k=dd], rows i0 + it*16 + lr  (b128 loads)
    bf16x8 aq[2][2];
    #pragma unroll
    for (int it = 0; it < 2; ++it)
        #pragma unroll
        for (int kt = 0; kt < 2; ++kt)
            aq[it][kt] = *(const bf16x8*)&qb[(size_t)(i0 + it * 16 + lr) * 64 + kt * 32 + lg * 8];

    bf16x8 ones;
    #pragma unroll
    for (int e = 0; e < 8; ++e) ones[e] = (short)0x3F80;   // bf16 1.0

    float m8[2][4];
    #pragma unroll
    for (int it = 0; it < 2; ++it)
        #pragma unroll
        for (int r = 0; r < 4; ++r) m8[it][r] = -3.0e38f;
    f32x4 accO[2][4] = {};
    f32x4 accL[2] = {};
    unsigned short* pw = p_s + w * (32 * 72);

    // staging: thread t stages 32B of K and 32B of V per tile
    int srow = t >> 2, scol = (t & 3) * 16;
    const unsigned short* kg = kb + srow * 64 + scol;            // K row j=srow
    const unsigned short* vg = vb + (size_t)srow * 1024 + scol;  // V row dd=srow
    int soff = srow * 72 + scol;

    // prologue: tile 0 -> buf0 directly; tile 1 -> regs
    {
        bf16x8 a0 = *(const bf16x8*)kg, a1 = *(const bf16x8*)(kg + 8);
        bf16x8 c0 = *(const bf16x8*)vg, c1 = *(const bf16x8*)(vg + 8);
        *(bf16x8*)&k_t[soff] = a0; *(bf16x8*)&k_t[soff + 8] = a1;
        *(bf16x8*)&v_s[soff] = c0; *(bf16x8*)&v_s[soff + 8] = c1;
    }
    bf16x8 nk0 = *(const bf16x8*)(kg + 4096), nk1 = *(const bf16x8*)(kg + 4096 + 8);
    bf16x8 nv0 = *(const bf16x8*)(vg + 64),   nv1 = *(const bf16x8*)(vg + 64 + 8);

    for (int tile = 0; tile < 16; ++tile) {
        __syncthreads();                       // buf[tile&1] ready; buf[(tile+1)&1] free
        const unsigned short* kc = k_t + (tile & 1) * 4608;
        const unsigned short* vc = v_s + (tile & 1) * 4608;

        // S = Q K^T  (log2 domain) — bk shared by both i-tiles; reads issue
        // ahead of the staging writes in the LDS pipe.
        f32x4 s[2][4] = {};
        __builtin_amdgcn_s_setprio(1);
        #pragma unroll
        for (int kt = 0; kt < 2; ++kt) {
            bf16x8 bk[4];
            #pragma unroll
            for (int jt = 0; jt < 4; ++jt)
                bk[jt] = *(const bf16x8*)&kc[(jt * 16 + lr) * 72 + kt * 32 + lg * 8];
            #pragma unroll
            for (int it = 0; it < 2; ++it)
                #pragma unroll
                for (int jt = 0; jt < 4; ++jt)
                    s[it][jt] = MFMA16(aq[it][kt], bk[jt], s[it][jt]);
        }
        __builtin_amdgcn_s_setprio(0);

        // stage tile t+1 into the other buffer; then prefetch t+2
        if (tile < 15) {
            unsigned short* kn = k_t + ((tile + 1) & 1) * 4608 + soff;
            unsigned short* vn = v_s + ((tile + 1) & 1) * 4608 + soff;
            *(bf16x8*)kn = nk0; *(bf16x8*)(kn + 8) = nk1;
            *(bf16x8*)vn = nv0; *(bf16x8*)(vn + 8) = nv1;
            if (tile < 14) {
                const unsigned short* kp = kg + (tile + 2) * 4096;
                const unsigned short* vp = vg + (tile + 2) * 64;
                nk0 = *(const bf16x8*)kp; nk1 = *(const bf16x8*)(kp + 8);
                nv0 = *(const bf16x8*)vp; nv1 = *(const bf16x8*)(vp + 8);
            }
        }

        // per-row tile max via DPP; defer-max: rescale only on growth
        float sm[2][4];
        float g = -3.0e38f;
        #pragma unroll
        for (int it = 0; it < 2; ++it)
            #pragma unroll
            for (int r = 0; r < 4; ++r) {
                float v0 = fmaxf(fmaxf(s[it][0][r], s[it][1][r]),
                                 fmaxf(s[it][2][r], s[it][3][r]));
                v0 = fmaxf(v0, ROR16(v0, 1));
                v0 = fmaxf(v0, ROR16(v0, 2));
                v0 = fmaxf(v0, ROR16(v0, 4));
                v0 = fmaxf(v0, ROR16(v0, 8));
                sm[it][r] = v0;
                g = fmaxf(g, v0 - m8[it][r]);
            }
        if (__any(g > 11.0f)) {
            #pragma unroll
            for (int it = 0; it < 2; ++it)
                #pragma unroll
                for (int r = 0; r < 4; ++r) {
                    float mn = fmaxf(m8[it][r], sm[it][r]);
                    float al = EXP2(m8[it][r] - mn);
                    accL[it][r] *= al;
                    #pragma unroll
                    for (int dt = 0; dt < 4; ++dt) accO[it][dt][r] *= al;
                    m8[it][r] = mn;
                }
        }

        // P = exp2(S - m), pack to bf16 in wave-private LDS
        #pragma unroll
        for (int it = 0; it < 2; ++it)
            #pragma unroll
            for (int jt = 0; jt < 4; ++jt) {
                unsigned u01 = pk2(EXP2(s[it][jt][0] - m8[it][0]),
                                   EXP2(s[it][jt][1] - m8[it][1]));
                unsigned u23 = pk2(EXP2(s[it][jt][2] - m8[it][2]),
                                   EXP2(s[it][jt][3] - m8[it][3]));
                int row = it * 16 + lg * 4;
                int col = jt * 16 + lr;
                pw[(row + 0) * 72 + col] = (unsigned short)u01;
                pw[(row + 1) * 72 + col] = (unsigned short)(u01 >> 16);
                pw[(row + 2) * 72 + col] = (unsigned short)u23;
                pw[(row + 3) * 72 + col] = (unsigned short)(u23 >> 16);
            }

        // O += P V^T ; L += P * 1  — bv shared by both i-tiles
        __builtin_amdgcn_s_setprio(1);
        #pragma unroll
        for (int kj = 0; kj < 2; ++kj) {
            bf16x8 bv[4];
            #pragma unroll
            for (int dt = 0; dt < 4; ++dt)
                bv[dt] = *(const bf16x8*)&vc[(dt * 16 + lr) * 72 + kj * 32 + lg * 8];
            #pragma unroll
            for (int it = 0; it < 2; ++it) {
                bf16x8 pa = *(const bf16x8*)&pw[(it * 16 + lr) * 72 + kj * 32 + lg * 8];
                accL[it] = MFMA16(pa, ones, accL[it]);
                #pragma unroll
                for (int dt = 0; dt < 4; ++dt)
                    accO[it][dt] = MFMA16(pa, bv[dt], accO[it][dt]);
            }
        }
        __builtin_amdgcn_s_setprio(0);
    }

    // epilogue: o_t[b][i][h*64+dd] = O[i][dd] / l
    #pragma unroll
    for (int it = 0; it < 2; ++it) {
        float inv[4];
        #pragma unroll
        for (int r = 0; r < 4; ++r) inv[r] = 1.0f / accL[it][r];
        #pragma unroll
        for (int dt = 0; dt < 4; ++dt)
            #pragma unroll
            for (int r = 0; r < 4; ++r) {
                int i = i0 + it * 16 + lg * 4 + r;
                o_t[((size_t)b * 1024 + i) * 512 + h * 64 + dt * 16 + lr] =
                    f2bf(accO[it][dt][r] * inv[r]);
            }
    }
}

// ---------------- K5: proj GEMM + bias + residual(xn) -----------------------
// 128x64 tiles, grid (16,4,8)=512 blocks -> 2 blocks/CU; glds staging.
__global__ __launch_bounds__(256) void proj_gemm(
    const unsigned short* __restrict__ W, const unsigned short* __restrict__ o_t,
    const float* __restrict__ b_out, const float* __restrict__ x,
    const float* __restrict__ gamma, const float* __restrict__ beta,
    const float2* __restrict__ stats, float* __restrict__ out) {
    __shared__ unsigned short a_t[128 * 64];   // [o][k]
    __shared__ unsigned short b_t[64 * 64];    // [j][k]
    int t = threadIdx.x, w = t >> 6, l = t & 63, lr = l & 15, lg = l >> 4;
    int jt = blockIdx.x, mt = blockIdx.y, b = blockIdx.z;
    int o0 = mt * 128, j0 = jt * 64;
    int wr = w >> 1, wc = w & 1;
    const unsigned short* Bsrc = o_t + (size_t)b * 1024 * 512;
    f32x4 acc[4][2] = {};
    // staging: wave w stages A chunks w*4..w*4+3 (8 rows each) and B chunks
    // w*2..w*2+1; lane l covers row chunk*8 + (l>>3), cols (l&7)*8..+7.
    const unsigned short* gA = W    + (size_t)(o0 + (l >> 3)) * 512 + (l & 7) * 8;
    const unsigned short* gB = Bsrc + (size_t)(j0 + (l >> 3)) * 512 + (l & 7) * 8;
    for (int kk = 0; kk < 512; kk += 64) {
        #pragma unroll
        for (int c = 0; c < 4; ++c)
            glds16(gA + (size_t)(w * 4 + c) * 4096 + kk, a_t + (w * 4 + c) * 512);
        #pragma unroll
        for (int c = 0; c < 2; ++c)
            glds16(gB + (size_t)(w * 2 + c) * 4096 + kk, b_t + (w * 2 + c) * 512);
        __syncthreads();
        __builtin_amdgcn_s_setprio(1);
        #pragma unroll
        for (int ks = 0; ks < 2; ++ks) {
            bf16x8 af[4], bfr[2];
            #pragma unroll
            for (int m = 0; m < 4; ++m)
                af[m] = *(const bf16x8*)&a_t[(wr * 64 + m * 16 + lr) * 64 + ks * 32 + lg * 8];
            #pragma unroll
            for (int n = 0; n < 2; ++n)
                bfr[n] = *(const bf16x8*)&b_t[(wc * 32 + n * 16 + lr) * 64 + ks * 32 + lg * 8];
            #pragma unroll
            for (int m = 0; m < 4; ++m)
                #pragma unroll
                for (int n = 0; n < 2; ++n)
                    acc[m][n] = MFMA16(af[m], bfr[n], acc[m][n]);
        }
        __builtin_amdgcn_s_setprio(0);
        __syncthreads();
    }
    #pragma unroll
    for (int m = 0; m < 4; ++m)
        #pragma unroll
        for (int r = 0; r < 4; ++r) {
            int o = o0 + wr * 64 + m * 16 + lg * 4 + r;
            float2 ms = stats[b * 8 + (o >> 6)];
            float g  = gamma[o] * ms.y;
            float bb = beta[o] - ms.x * g + b_out[o];
            const float* xr = x + ((size_t)b * 512 + o) * 1024;
            #pragma unroll
            for (int n = 0; n < 2; ++n) {
                int j = j0 + wc * 32 + n * 16 + lr;
                float xn = fmaf(xr[j], g, bb);
                out[((size_t)b * 512 + o) * 1024 + j] = acc[m][n][r] + xn;
            }
        }
}

// ---------------------------------------------------------------------------
extern "C" void kernel_launch(void* const* d_in, const int* in_sizes, int n_in,
                              void* d_out, int out_size, void* d_ws, size_t ws_size,
                              hipStream_t stream) {
    const float* x     = (const float*)d_in[0];
    const float* gamma = (const float*)d_in[1];
    const float* beta  = (const float*)d_in[2];
    const float* w_qkv = (const float*)d_in[3];
    const float* w_out = (const float*)d_in[4];
    const float* b_out = (const float*)d_in[5];
    float* out = (float*)d_out;

    char* ws = (char*)d_ws;
    unsigned short* wqb     = (unsigned short*)(ws);                  // 1.5 MB
    unsigned short* wob     = (unsigned short*)(ws + 0x180000);       // 0.5 MB
    float2*         stats   = (float2*)(ws + 0x200000);               // 512 B
    float2*         partial = (float2*)(ws + 0x201000);               // 4 KB
    unsigned short* xnT     = (unsigned short*)(ws + 0x210000);       // 8 MB
    unsigned short* qT      = (unsigned short*)(ws + 0xA10000);       // 8 MB
    unsigned short* kT      = (unsigned short*)(ws + 0x1210000);      // 8 MB
    unsigned short* vK      = (unsigned short*)(ws + 0x1A10000);      // 8 MB
    unsigned short* o_t     = (unsigned short*)(ws + 0x2210000);      // 8 MB
    // total ~44.1 MB

    prep_kern<<<1280, 256, 0, stream>>>(x, w_qkv, w_out, partial, wqb, wob);
    gn_norm_t<<<dim3(16, 8, 8), 256, 0, stream>>>(x, gamma, beta, partial, stats, xnT);
    qkv_gemm<<<dim3(8, 12, 8), 256, 0, stream>>>(wqb, xnT, qT, kT, vK);
    attn_kern<<<512, 256, 0, stream>>>(qT, kT, vK, o_t);
    proj_gemm<<<dim3(16, 4, 8), 256, 0, stream>>>(wob, o_t, b_out, x, gamma, beta, stats, out);
}

// Round 17
// 84.741 us; speedup vs baseline: 1.3065x; 1.0204x over previous
//
#include <hip/hip_runtime.h>
#include <hip/hip_bf16.h>

// ---------------------------------------------------------------------------
// Fused: GroupNorm -> QKV (1x1 conv) -> 8-head attention (n=1024,d=64)
//        -> proj (1x1 conv) + bias + residual(xn)
// b=8, c=512, n=1024, GROUPS=8, HEADS=8, dim_head=64. bf16 MFMA, fp32 accum.
// R17: attention max-reduce moved OFF the QK->P->PV critical path: P uses the
//      running m8 (init 0, safe: |s_log2| bounded); DPP tile-max runs
//      concurrently; defer-max rescale evaluated after PV (one-tile lag,
//      mathematically identical). Rest identical to R16.
// ---------------------------------------------------------------------------

typedef short bf16x8 __attribute__((ext_vector_type(8)));
typedef float f32x4 __attribute__((ext_vector_type(4)));
typedef unsigned short u16x4 __attribute__((ext_vector_type(4)));

#define MFMA16(a, b, c) __builtin_amdgcn_mfma_f32_16x16x32_bf16(a, b, c, 0, 0, 0)
#define EXP2(x) __builtin_amdgcn_exp2f(x)
// rotate-right by N within each 16-lane row (pure VALU DPP)
#define ROR16(v, N) __int_as_float(__builtin_amdgcn_mov_dpp(__float_as_int(v), 0x120 + (N), 0xF, 0xF, false))

__device__ __forceinline__ unsigned short f2bf(float f) {
    unsigned u = __float_as_uint(f);
    u += 0x7fffu + ((u >> 16) & 1u);   // round-to-nearest-even
    return (unsigned short)(u >> 16);
}

// pack two fp32 -> u32 of two bf16 (lo=a, hi=b), RNE via HIP intrinsic
__device__ __forceinline__ unsigned pk2(float a, float b) {
    __hip_bfloat162 h = __float22bfloat162_rn(float2{a, b});
    unsigned r;
    __builtin_memcpy(&r, &h, 4);
    return r;
}

// async global -> LDS, 16B per lane; lptr must be wave-uniform (HW adds lane*16)
__device__ __forceinline__ void glds16(const unsigned short* g, unsigned short* l) {
    __builtin_amdgcn_global_load_lds(
        (const __attribute__((address_space(1))) unsigned int*)g,
        (__attribute__((address_space(3))) unsigned int*)l, 16, 0, 0);
}

// ---------------- K0: stats partials (512 blocks) + weight cvt (768) --------
__global__ __launch_bounds__(256) void prep_kern(
    const float* __restrict__ x, const float* __restrict__ wq,
    const float* __restrict__ wo, float2* __restrict__ partials,
    unsigned short* __restrict__ wqb, unsigned short* __restrict__ wob) {
    int blk = blockIdx.x, t = threadIdx.x;
    if (blk < 512) {
        __shared__ float ss[256], sq[256];
        int bg = blk >> 3, chunk = blk & 7;
        const float4* p = reinterpret_cast<const float4*>(
            x + (size_t)bg * 65536 + chunk * 8192);
        float s = 0.f, q = 0.f;
        #pragma unroll
        for (int i = 0; i < 8; ++i) {
            float4 v = p[t + i * 256];
            s += v.x + v.y + v.z + v.w;
            q += v.x * v.x + v.y * v.y + v.z * v.z + v.w * v.w;
        }
        ss[t] = s; sq[t] = q; __syncthreads();
        for (int o = 128; o > 0; o >>= 1) {
            if (t < o) { ss[t] += ss[t + o]; sq[t] += sq[t + o]; }
            __syncthreads();
        }
        if (t == 0) partials[blk] = make_float2(ss[0], sq[0]);
    } else {
        int i = (blk - 512) * 256 + t;        // 0..196607
        {
            float4 v = reinterpret_cast<const float4*>(wq)[i];
            unsigned short* d = wqb + (size_t)i * 4;
            d[0] = f2bf(v.x); d[1] = f2bf(v.y); d[2] = f2bf(v.z); d[3] = f2bf(v.w);
        }
        if (i < 65536) {
            float4 v = reinterpret_cast<const float4*>(wo)[i];
            unsigned short* d = wob + (size_t)i * 4;
            d[0] = f2bf(v.x); d[1] = f2bf(v.y); d[2] = f2bf(v.z); d[3] = f2bf(v.w);
        }
    }
}

// ---------------- K2: normalize + transpose -> xnT[b][n][c] bf16 ------------
__global__ __launch_bounds__(256) void gn_norm_t(
    const float* __restrict__ x, const float* __restrict__ gamma,
    const float* __restrict__ beta, const float2* __restrict__ partials,
    float2* __restrict__ stats, unsigned short* __restrict__ xnT) {
    __shared__ unsigned short tile[64 * 72];
    int t = threadIdx.x;
    int jt = blockIdx.x, ct = blockIdx.y, b = blockIdx.z;
    float s = 0.f, q = 0.f;
    #pragma unroll
    for (int k = 0; k < 8; ++k) {
        float2 p = partials[(b * 8 + ct) * 8 + k];
        s += p.x; q += p.y;
    }
    float mean = s * (1.f / 65536.f);
    float var  = q * (1.f / 65536.f) - mean * mean;
    float rstd = rsqrtf(var + 1e-5f);
    if (jt == 0 && t == 0) stats[b * 8 + ct] = make_float2(mean, rstd);
    int c = t >> 2, jseg = (t & 3) * 16;
    int ch = ct * 64 + c;
    float g  = gamma[ch] * rstd;
    float bb = beta[ch] - mean * g;
    const float* src = x + ((size_t)(b * 512 + ch)) * 1024 + jt * 64 + jseg;
    float4 v0 = *(const float4*)(src);
    float4 v1 = *(const float4*)(src + 4);
    float4 v2 = *(const float4*)(src + 8);
    float4 v3 = *(const float4*)(src + 12);
    float vv[16] = {v0.x,v0.y,v0.z,v0.w, v1.x,v1.y,v1.z,v1.w,
                    v2.x,v2.y,v2.z,v2.w, v3.x,v3.y,v3.z,v3.w};
    #pragma unroll
    for (int e = 0; e < 16; ++e)
        tile[(jseg + e) * 72 + c] = f2bf(fmaf(vv[e], g, bb));
    __syncthreads();
    int j = t >> 2, cseg = (t & 3) * 16;
    unsigned short* dst = xnT + ((size_t)b * 1024 + jt * 64 + j) * 512 + ct * 64 + cseg;
    bf16x8 a0 = *(const bf16x8*)&tile[j * 72 + cseg];
    bf16x8 a1 = *(const bf16x8*)&tile[j * 72 + cseg + 8];
    *(bf16x8*)dst = a0;
    *(bf16x8*)(dst + 8) = a1;
}

// ---------------- K3: QKV GEMM -> qT (scaled), kT, v ------------------------
// Staging via global_load_lds into LINEAR LDS tiles (m97 pattern).
__global__ __launch_bounds__(256) void qkv_gemm(
    const unsigned short* __restrict__ W, const unsigned short* __restrict__ xnT,
    unsigned short* __restrict__ qT, unsigned short* __restrict__ kT,
    unsigned short* __restrict__ vK) {
    __shared__ unsigned short a_t[128 * 64];   // [o][k] linear
    __shared__ unsigned short b_t[128 * 64];   // [j][k] linear
    int t = threadIdx.x, w = t >> 6, l = t & 63, lr = l & 15, lg = l >> 4;
    int jt = blockIdx.x, mt = blockIdx.y, b = blockIdx.z;
    int o0 = mt * 128, j0 = jt * 128;
    int wr = w >> 1, wc = w & 1;
    const unsigned short* Bsrc = xnT + (size_t)b * 1024 * 512;
    f32x4 acc[4][4] = {};
    const unsigned short* gA = W    + (size_t)(o0 + w * 32 + (l >> 3)) * 512 + (l & 7) * 8;
    const unsigned short* gB = Bsrc + (size_t)(j0 + w * 32 + (l >> 3)) * 512 + (l & 7) * 8;
    for (int kk = 0; kk < 512; kk += 64) {
        #pragma unroll
        for (int k = 0; k < 4; ++k) {
            glds16(gA + (size_t)k * 4096 + kk, a_t + w * 2048 + k * 512);
            glds16(gB + (size_t)k * 4096 + kk, b_t + w * 2048 + k * 512);
        }
        __syncthreads();                       // drains vmcnt -> LDS filled
        __builtin_amdgcn_s_setprio(1);
        #pragma unroll
        for (int ks = 0; ks < 2; ++ks) {
            bf16x8 af[4], bfr[4];
            #pragma unroll
            for (int m = 0; m < 4; ++m)
                af[m] = *(const bf16x8*)&a_t[(wr * 64 + m * 16 + lr) * 64 + ks * 32 + lg * 8];
            #pragma unroll
            for (int n = 0; n < 4; ++n)
                bfr[n] = *(const bf16x8*)&b_t[(wc * 64 + n * 16 + lr) * 64 + ks * 32 + lg * 8];
            #pragma unroll
            for (int m = 0; m < 4; ++m)
                #pragma unroll
                for (int n = 0; n < 4; ++n)
                    acc[m][n] = MFMA16(af[m], bfr[n], acc[m][n]);
        }
        __builtin_amdgcn_s_setprio(0);
        __syncthreads();                       // all reads done before next glds
    }
    int part = mt >> 2;                       // 0=q, 1=k, 2=v
    int hh = ((mt * 2) + wr) & 7;             // head for this wave-row half
    if (part < 2) {
        unsigned short* dst = (part == 0) ? qT : kT;
        float sc = (part == 0) ? 0.1803368801f : 1.0f;  // 0.125*log2(e)
        #pragma unroll
        for (int m = 0; m < 4; ++m)
            #pragma unroll
            for (int n = 0; n < 4; ++n) {
                int j = j0 + wc * 64 + n * 16 + lr;
                u16x4 pkt;
                pkt[0] = f2bf(acc[m][n][0] * sc);
                pkt[1] = f2bf(acc[m][n][1] * sc);
                pkt[2] = f2bf(acc[m][n][2] * sc);
                pkt[3] = f2bf(acc[m][n][3] * sc);
                *(u16x4*)&dst[(((size_t)(b * 8 + hh)) * 1024 + j) * 64 + m * 16 + lg * 4] = pkt;
            }
    } else {
        #pragma unroll
        for (int m = 0; m < 4; ++m)
            #pragma unroll
            for (int n = 0; n < 4; ++n)
                #pragma unroll
                for (int r = 0; r < 4; ++r) {
                    int dd = m * 16 + lg * 4 + r;
                    int j = j0 + wc * 64 + n * 16 + lr;
                    vK[(((size_t)(b * 8 + hh)) * 64 + dd) * 1024 + j] = f2bf(acc[m][n][r]);
                }
    }
}

// ---------------- K4: flash attention, 4 waves x 32 q-rows, dbuf LDS --------
// Per tile: barrier -> QK -> P=exp2(s-m8) pack (m8 = running max, init 0;
// |s_log2|<~12 keeps p bounded) -> stage t+1 -> PV; DPP tile-max computed
// concurrently; defer-max rescale AFTER PV (one-tile lag, same math).
__global__ __launch_bounds__(256, 2) void attn_kern(
    const unsigned short* __restrict__ qT, const unsigned short* __restrict__ kT,
    const unsigned short* __restrict__ vK, unsigned short* __restrict__ o_t) {
    __shared__ unsigned short k_t[2 * 64 * 72];   // [buf][j][dd]
    __shared__ unsigned short v_s[2 * 64 * 72];   // [buf][dd][j]
    __shared__ unsigned short p_s[4 * 32 * 72];   // per-wave [i][j]
    int t = threadIdx.x, w = t >> 6, l = t & 63, lr = l & 15, lg = (l >> 4) & 3;
    // XCD-chunked swizzle: 64 consecutive decoded blocks (1 bh) per XCD
    int id = blockIdx.x;
    int lin = (id & 7) * 64 + (id >> 3);
    int qt = lin & 7, bh = lin >> 3;
    int b = bh >> 3, h = bh & 7;
    const unsigned short* qb = qT + (size_t)bh * 1024 * 64;
    const unsigned short* kb = kT + (size_t)bh * 1024 * 64;
    const unsigned short* vb = vK + (size_t)bh * 64 * 1024;
    int i0 = qt * 128 + w * 32;

    // Q fragments: A[row=i][k=dd], rows i0 + it*16 + lr  (b128 loads)
    bf16x8 aq[2][2];
    #pragma unroll
    for (int it = 0; it < 2; ++it)
        #pragma unroll
        for (int kt = 0; kt < 2; ++kt)
            aq[it][kt] = *(const bf16x8*)&qb[(size_t)(i0 + it * 16 + lr) * 64 + kt * 32 + lg * 8];

    bf16x8 ones;
    #pragma unroll
    for (int e = 0; e < 8; ++e) ones[e] = (short)0x3F80;   // bf16 1.0

    float m8[2][4];
    #pragma unroll
    for (int it = 0; it < 2; ++it)
        #pragma unroll
        for (int r = 0; r < 4; ++r) m8[it][r] = 0.0f;   // safe: |s_log2| bounded
    f32x4 accO[2][4] = {};
    f32x4 accL[2] = {};
    unsigned short* pw = p_s + w * (32 * 72);

    // staging: thread t stages 32B of K and 32B of V per tile
    int srow = t >> 2, scol = (t & 3) * 16;
    const unsigned short* kg = kb + srow * 64 + scol;            // K row j=srow
    const unsigned short* vg = vb + (size_t)srow * 1024 + scol;  // V row dd=srow
    int soff = srow * 72 + scol;

    // prologue: tile 0 -> buf0 directly; tile 1 -> regs
    {
        bf16x8 a0 = *(const bf16x8*)kg, a1 = *(const bf16x8*)(kg + 8);
        bf16x8 c0 = *(const bf16x8*)vg, c1 = *(const bf16x8*)(vg + 8);
        *(bf16x8*)&k_t[soff] = a0; *(bf16x8*)&k_t[soff + 8] = a1;
        *(bf16x8*)&v_s[soff] = c0; *(bf16x8*)&v_s[soff + 8] = c1;
    }
    bf16x8 nk0 = *(const bf16x8*)(kg + 4096), nk1 = *(const bf16x8*)(kg + 4096 + 8);
    bf16x8 nv0 = *(const bf16x8*)(vg + 64),   nv1 = *(const bf16x8*)(vg + 64 + 8);

    for (int tile = 0; tile < 16; ++tile) {
        __syncthreads();                       // buf[tile&1] ready; buf[(tile+1)&1] free
        const unsigned short* kc = k_t + (tile & 1) * 4608;
        const unsigned short* vc = v_s + (tile & 1) * 4608;

        // S = Q K^T  (log2 domain) — bk shared by both i-tiles
        f32x4 s[2][4] = {};
        __builtin_amdgcn_s_setprio(1);
        #pragma unroll
        for (int kt = 0; kt < 2; ++kt) {
            bf16x8 bk[4];
            #pragma unroll
            for (int jt = 0; jt < 4; ++jt)
                bk[jt] = *(const bf16x8*)&kc[(jt * 16 + lr) * 72 + kt * 32 + lg * 8];
            #pragma unroll
            for (int it = 0; it < 2; ++it)
                #pragma unroll
                for (int jt = 0; jt < 4; ++jt)
                    s[it][jt] = MFMA16(aq[it][kt], bk[jt], s[it][jt]);
        }
        __builtin_amdgcn_s_setprio(0);

        // P = exp2(S - m8) with the RUNNING m8 (no wait on this tile's max)
        #pragma unroll
        for (int it = 0; it < 2; ++it)
            #pragma unroll
            for (int jt = 0; jt < 4; ++jt) {
                unsigned u01 = pk2(EXP2(s[it][jt][0] - m8[it][0]),
                                   EXP2(s[it][jt][1] - m8[it][1]));
                unsigned u23 = pk2(EXP2(s[it][jt][2] - m8[it][2]),
                                   EXP2(s[it][jt][3] - m8[it][3]));
                int row = it * 16 + lg * 4;
                int col = jt * 16 + lr;
                pw[(row + 0) * 72 + col] = (unsigned short)u01;
                pw[(row + 1) * 72 + col] = (unsigned short)(u01 >> 16);
                pw[(row + 2) * 72 + col] = (unsigned short)u23;
                pw[(row + 3) * 72 + col] = (unsigned short)(u23 >> 16);
            }

        // stage tile t+1 into the other buffer; then prefetch t+2
        if (tile < 15) {
            unsigned short* kn = k_t + ((tile + 1) & 1) * 4608 + soff;
            unsigned short* vn = v_s + ((tile + 1) & 1) * 4608 + soff;
            *(bf16x8*)kn = nk0; *(bf16x8*)(kn + 8) = nk1;
            *(bf16x8*)vn = nv0; *(bf16x8*)(vn + 8) = nv1;
            if (tile < 14) {
                const unsigned short* kp = kg + (tile + 2) * 4096;
                const unsigned short* vp = vg + (tile + 2) * 64;
                nk0 = *(const bf16x8*)kp; nk1 = *(const bf16x8*)(kp + 8);
                nv0 = *(const bf16x8*)vp; nv1 = *(const bf16x8*)(vp + 8);
            }
        }

        // tile max via DPP — independent of the P/PV chain, overlaps it
        float sm[2][4];
        #pragma unroll
        for (int it = 0; it < 2; ++it)
            #pragma unroll
            for (int r = 0; r < 4; ++r) {
                float v0 = fmaxf(fmaxf(s[it][0][r], s[it][1][r]),
                                 fmaxf(s[it][2][r], s[it][3][r]));
                v0 = fmaxf(v0, ROR16(v0, 1));
                v0 = fmaxf(v0, ROR16(v0, 2));
                v0 = fmaxf(v0, ROR16(v0, 4));
                v0 = fmaxf(v0, ROR16(v0, 8));
                sm[it][r] = v0;
            }

        // O += P V^T ; L += P * 1  — bv shared by both i-tiles
        __builtin_amdgcn_s_setprio(1);
        #pragma unroll
        for (int kj = 0; kj < 2; ++kj) {
            bf16x8 bv[4];
            #pragma unroll
            for (int dt = 0; dt < 4; ++dt)
                bv[dt] = *(const bf16x8*)&vc[(dt * 16 + lr) * 72 + kj * 32 + lg * 8];
            #pragma unroll
            for (int it = 0; it < 2; ++it) {
                bf16x8 pa = *(const bf16x8*)&pw[(it * 16 + lr) * 72 + kj * 32 + lg * 8];
                accL[it] = MFMA16(pa, ones, accL[it]);
                #pragma unroll
                for (int dt = 0; dt < 4; ++dt)
                    accO[it][dt] = MFMA16(pa, bv[dt], accO[it][dt]);
            }
        }
        __builtin_amdgcn_s_setprio(0);

        // defer-max, evaluated after PV (one-tile lag): rescale on growth
        float g = -3.0e38f;
        #pragma unroll
        for (int it = 0; it < 2; ++it)
            #pragma unroll
            for (int r = 0; r < 4; ++r)
                g = fmaxf(g, sm[it][r] - m8[it][r]);
        if (__any(g > 11.0f)) {
            #pragma unroll
            for (int it = 0; it < 2; ++it)
                #pragma unroll
                for (int r = 0; r < 4; ++r) {
                    float mn = fmaxf(m8[it][r], sm[it][r]);
                    float al = EXP2(m8[it][r] - mn);
                    accL[it][r] *= al;
                    #pragma unroll
                    for (int dt = 0; dt < 4; ++dt) accO[it][dt][r] *= al;
                    m8[it][r] = mn;
                }
        }
    }

    // epilogue: o_t[b][i][h*64+dd] = O[i][dd] / l
    #pragma unroll
    for (int it = 0; it < 2; ++it) {
        float inv[4];
        #pragma unroll
        for (int r = 0; r < 4; ++r) inv[r] = 1.0f / accL[it][r];
        #pragma unroll
        for (int dt = 0; dt < 4; ++dt)
            #pragma unroll
            for (int r = 0; r < 4; ++r) {
                int i = i0 + it * 16 + lg * 4 + r;
                o_t[((size_t)b * 1024 + i) * 512 + h * 64 + dt * 16 + lr] =
                    f2bf(accO[it][dt][r] * inv[r]);
            }
    }
}

// ---------------- K5: proj GEMM + bias + residual(xn) -----------------------
// 128x64 tiles, grid (16,4,8)=512 blocks -> 2 blocks/CU; glds staging.
__global__ __launch_bounds__(256) void proj_gemm(
    const unsigned short* __restrict__ W, const unsigned short* __restrict__ o_t,
    const float* __restrict__ b_out, const float* __restrict__ x,
    const float* __restrict__ gamma, const float* __restrict__ beta,
    const float2* __restrict__ stats, float* __restrict__ out) {
    __shared__ unsigned short a_t[128 * 64];   // [o][k]
    __shared__ unsigned short b_t[64 * 64];    // [j][k]
    int t = threadIdx.x, w = t >> 6, l = t & 63, lr = l & 15, lg = l >> 4;
    int jt = blockIdx.x, mt = blockIdx.y, b = blockIdx.z;
    int o0 = mt * 128, j0 = jt * 64;
    int wr = w >> 1, wc = w & 1;
    const unsigned short* Bsrc = o_t + (size_t)b * 1024 * 512;
    f32x4 acc[4][2] = {};
    const unsigned short* gA = W    + (size_t)(o0 + (l >> 3)) * 512 + (l & 7) * 8;
    const unsigned short* gB = Bsrc + (size_t)(j0 + (l >> 3)) * 512 + (l & 7) * 8;
    for (int kk = 0; kk < 512; kk += 64) {
        #pragma unroll
        for (int c = 0; c < 4; ++c)
            glds16(gA + (size_t)(w * 4 + c) * 4096 + kk, a_t + (w * 4 + c) * 512);
        #pragma unroll
        for (int c = 0; c < 2; ++c)
            glds16(gB + (size_t)(w * 2 + c) * 4096 + kk, b_t + (w * 2 + c) * 512);
        __syncthreads();
        __builtin_amdgcn_s_setprio(1);
        #pragma unroll
        for (int ks = 0; ks < 2; ++ks) {
            bf16x8 af[4], bfr[2];
            #pragma unroll
            for (int m = 0; m < 4; ++m)
                af[m] = *(const bf16x8*)&a_t[(wr * 64 + m * 16 + lr) * 64 + ks * 32 + lg * 8];
            #pragma unroll
            for (int n = 0; n < 2; ++n)
                bfr[n] = *(const bf16x8*)&b_t[(wc * 32 + n * 16 + lr) * 64 + ks * 32 + lg * 8];
            #pragma unroll
            for (int m = 0; m < 4; ++m)
                #pragma unroll
                for (int n = 0; n < 2; ++n)
                    acc[m][n] = MFMA16(af[m], bfr[n], acc[m][n]);
        }
        __builtin_amdgcn_s_setprio(0);
        __syncthreads();
    }
    #pragma unroll
    for (int m = 0; m < 4; ++m)
        #pragma unroll
        for (int r = 0; r < 4; ++r) {
            int o = o0 + wr * 64 + m * 16 + lg * 4 + r;
            float2 ms = stats[b * 8 + (o >> 6)];
            float g  = gamma[o] * ms.y;
            float bb = beta[o] - ms.x * g + b_out[o];
            const float* xr = x + ((size_t)b * 512 + o) * 1024;
            #pragma unroll
            for (int n = 0; n < 2; ++n) {
                int j = j0 + wc * 32 + n * 16 + lr;
                float xn = fmaf(xr[j], g, bb);
                out[((size_t)b * 512 + o) * 1024 + j] = acc[m][n][r] + xn;
            }
        }
}

// ---------------------------------------------------------------------------
extern "C" void kernel_launch(void* const* d_in, const int* in_sizes, int n_in,
                              void* d_out, int out_size, void* d_ws, size_t ws_size,
                              hipStream_t stream) {
    const float* x     = (const float*)d_in[0];
    const float* gamma = (const float*)d_in[1];
    const float* beta  = (const float*)d_in[2];
    const float* w_qkv = (const float*)d_in[3];
    const float* w_out = (const float*)d_in[4];
    const float* b_out = (const float*)d_in[5];
    float* out = (float*)d_out;

    char* ws = (char*)d_ws;
    unsigned short* wqb     = (unsigned short*)(ws);                  // 1.5 MB
    unsigned short* wob     = (unsigned short*)(ws + 0x180000);       // 0.5 MB
    float2*         stats   = (float2*)(ws + 0x200000);               // 512 B
    float2*         partial = (float2*)(ws + 0x201000);               // 4 KB
    unsigned short* xnT     = (unsigned short*)(ws + 0x210000);       // 8 MB
    unsigned short* qT      = (unsigned short*)(ws + 0xA10000);       // 8 MB
    unsigned short* kT      = (unsigned short*)(ws + 0x1210000);      // 8 MB
    unsigned short* vK      = (unsigned short*)(ws + 0x1A10000);      // 8 MB
    unsigned short* o_t     = (unsigned short*)(ws + 0x2210000);      // 8 MB
    // total ~44.1 MB

    prep_kern<<<1280, 256, 0, stream>>>(x, w_qkv, w_out, partial, wqb, wob);
    gn_norm_t<<<dim3(16, 8, 8), 256, 0, stream>>>(x, gamma, beta, partial, stats, xnT);
    qkv_gemm<<<dim3(8, 12, 8), 256, 0, stream>>>(wqb, xnT, qT, kT, vK);
    attn_kern<<<512, 256, 0, stream>>>(qT, kT, vK, o_t);
    proj_gemm<<<dim3(16, 4, 8), 256, 0, stream>>>(wob, o_t, b_out, x, gamma, beta, stats, out);
}